// Round 1
// baseline (1121.490 us; speedup 1.0000x reference)
//
#include <hip/hip_runtime.h>

#define NN 50000
#define NE 800000
#define NG 128
#define IN_DIM 12
#define C 64
#define NEG_SLOPE 0.01f

__device__ __forceinline__ float lrelu(float v) {
    return v > 0.f ? v : NEG_SLOPE * v;
}

// h[n][c] = leaky_relu( concat(state,action)[n] @ W_in + b_in )   one wave per node
__global__ void readin_kernel(const float* __restrict__ state,
                              const float* __restrict__ action,
                              const float* __restrict__ W_in,
                              const float* __restrict__ b_in,
                              float* __restrict__ h) {
    __shared__ float sW[IN_DIM * C];
    __shared__ float sb[C];
    int tid = threadIdx.x;
    for (int i = tid; i < IN_DIM * C; i += blockDim.x) sW[i] = W_in[i];
    if (tid < C) sb[tid] = b_in[tid];
    __syncthreads();

    int node = blockIdx.x * (blockDim.x >> 6) + (tid >> 6);
    int c = tid & 63;
    if (node >= NN) return;

    float x[IN_DIM];
#pragma unroll
    for (int k = 0; k < 8; k++) x[k] = state[node * 8 + k];
#pragma unroll
    for (int k = 0; k < 4; k++) x[8 + k] = action[node * 4 + k];

    float acc = sb[c];
#pragma unroll
    for (int k = 0; k < IN_DIM; k++) acc += x[k] * sW[k * C + c];
    h[node * C + c] = lrelu(acc);
}

// agg_e[dst[e]][k] += edge_attr[e][k]   (layer-invariant, done once)
__global__ void scatter_ea_kernel(const int* __restrict__ dst,
                                  const float* __restrict__ edge_attr,
                                  float* __restrict__ agg_e) {
    int idx = blockIdx.x * blockDim.x + threadIdx.x;
    int e = idx >> 4, k = idx & 15;
    if (e >= NE || k >= IN_DIM) return;
    atomicAdd(&agg_e[dst[e] * IN_DIM + k], edge_attr[e * IN_DIM + k]);
}

// agg_h[dst[e]][c] += h[src[e]][c]   one wave per edge, lane = channel
__global__ void scatter_h_kernel(const int* __restrict__ src,
                                 const int* __restrict__ dst,
                                 const float* __restrict__ h,
                                 float* __restrict__ agg) {
    int wid = (blockIdx.x * blockDim.x + threadIdx.x) >> 6;
    int lane = threadIdx.x & 63;
    if (wid >= NE) return;
    int s = src[wid];
    int d = dst[wid];
    atomicAdd(&agg[d * C + lane], h[s * C + lane]);
}

// h_out = leaky_relu( h @ W_self + agg_h @ W_nbr + agg_e @ W_edge + b_conv )
__global__ void node_update_kernel(const float* __restrict__ h,
                                   const float* __restrict__ agg_h,
                                   const float* __restrict__ agg_e,
                                   const float* __restrict__ W_self,
                                   const float* __restrict__ W_nbr,
                                   const float* __restrict__ W_edge,
                                   const float* __restrict__ b_conv,
                                   float* __restrict__ h_out) {
    __shared__ float sWs[C * C];
    __shared__ float sWn[C * C];
    __shared__ float sWe[IN_DIM * C];
    __shared__ float sb[C];
    int tid = threadIdx.x;
    for (int i = tid; i < C * C; i += blockDim.x) {
        sWs[i] = W_self[i];
        sWn[i] = W_nbr[i];
    }
    for (int i = tid; i < IN_DIM * C; i += blockDim.x) sWe[i] = W_edge[i];
    if (tid < C) sb[tid] = b_conv[tid];
    __syncthreads();

    int node = blockIdx.x * (blockDim.x >> 6) + (tid >> 6);
    int c = tid & 63;
    if (node >= NN) return;

    float hv = h[node * C + c];
    float av = agg_h[node * C + c];
    float ev = (c < IN_DIM) ? agg_e[node * IN_DIM + c] : 0.f;

    float acc = sb[c];
#pragma unroll
    for (int k = 0; k < C; k++) {
        float hk = __shfl(hv, k);
        float ak = __shfl(av, k);
        acc += hk * sWs[k * C + c] + ak * sWn[k * C + c];
    }
#pragma unroll
    for (int k = 0; k < IN_DIM; k++) {
        acc += __shfl(ev, k) * sWe[k * C + c];
    }
    h_out[node * C + c] = lrelu(acc);
}

// per-node scalar y = h@W_out + b_out; scatter into per-graph sums/counts
__global__ void readout_kernel(const float* __restrict__ h,
                               const float* __restrict__ W_out,
                               const float* __restrict__ b_out,
                               const int* __restrict__ batch,
                               float* __restrict__ sums,
                               float* __restrict__ counts) {
    int node = blockIdx.x * (blockDim.x >> 6) + (threadIdx.x >> 6);
    int c = threadIdx.x & 63;
    if (node >= NN) return;
    float v = h[node * C + c] * W_out[c];
#pragma unroll
    for (int off = 32; off; off >>= 1) v += __shfl_down(v, off);
    if (c == 0) {
        int g = batch[node];
        atomicAdd(&sums[g], v + b_out[0]);
        atomicAdd(&counts[g], 1.0f);
    }
}

__global__ void finalize_kernel(const float* __restrict__ sums,
                                const float* __restrict__ counts,
                                float* __restrict__ out) {
    int g = threadIdx.x;
    if (g < NG) out[g] = sums[g] / fmaxf(counts[g], 1.0f);
}

extern "C" void kernel_launch(void* const* d_in, const int* in_sizes, int n_in,
                              void* d_out, int out_size, void* d_ws, size_t ws_size,
                              hipStream_t stream) {
    const float* state     = (const float*)d_in[0];
    const float* action    = (const float*)d_in[1];
    const int*   edge_index= (const int*)d_in[2];
    const float* edge_attr = (const float*)d_in[3];
    const int*   batch     = (const int*)d_in[4];
    const float* W_in      = (const float*)d_in[5];
    const float* b_in      = (const float*)d_in[6];
    const float* W_self    = (const float*)d_in[7];
    const float* W_nbr     = (const float*)d_in[8];
    const float* W_edge    = (const float*)d_in[9];
    const float* b_conv    = (const float*)d_in[10];
    const float* W_out     = (const float*)d_in[11];
    const float* b_out     = (const float*)d_in[12];
    float* out = (float*)d_out;

    const int* src = edge_index;        // edge_index[0,:]
    const int* dst = edge_index + NE;   // edge_index[1,:]

    // workspace layout (floats)
    float* ws    = (float*)d_ws;
    float* h0    = ws;                  // NN*C
    float* h1    = h0 + NN * C;         // NN*C
    float* agg_h = h1 + NN * C;         // NN*C
    float* agg_e = agg_h + NN * C;      // NN*IN_DIM
    float* sums  = agg_e + NN * IN_DIM; // NG
    float* counts= sums + NG;           // NG

    // zero the accumulators (ws is poisoned 0xAA before every call)
    hipMemsetAsync(agg_e, 0, NN * IN_DIM * sizeof(float), stream);
    hipMemsetAsync(sums, 0, 2 * NG * sizeof(float), stream);

    const int THREADS = 256;
    const int NODES_PER_BLK = THREADS / 64;
    int node_blocks = (NN + NODES_PER_BLK - 1) / NODES_PER_BLK;
    int edge_blocks = (NE + NODES_PER_BLK - 1) / NODES_PER_BLK;

    // read-in
    readin_kernel<<<node_blocks, THREADS, 0, stream>>>(state, action, W_in, b_in, h0);

    // layer-invariant edge_attr scatter
    int ea_blocks = (NE * 16 + THREADS - 1) / THREADS;
    scatter_ea_kernel<<<ea_blocks, THREADS, 0, stream>>>(dst, edge_attr, agg_e);

    // layer 0
    hipMemsetAsync(agg_h, 0, NN * C * sizeof(float), stream);
    scatter_h_kernel<<<edge_blocks, THREADS, 0, stream>>>(src, dst, h0, agg_h);
    node_update_kernel<<<node_blocks, THREADS, 0, stream>>>(
        h0, agg_h, agg_e,
        W_self, W_nbr, W_edge, b_conv, h1);

    // layer 1
    hipMemsetAsync(agg_h, 0, NN * C * sizeof(float), stream);
    scatter_h_kernel<<<edge_blocks, THREADS, 0, stream>>>(src, dst, h1, agg_h);
    node_update_kernel<<<node_blocks, THREADS, 0, stream>>>(
        h1, agg_h, agg_e,
        W_self + C * C, W_nbr + C * C, W_edge + IN_DIM * C, b_conv + C, h0);

    // read-out
    readout_kernel<<<node_blocks, THREADS, 0, stream>>>(h0, W_out, b_out, batch, sums, counts);
    finalize_kernel<<<1, 128, 0, stream>>>(sums, counts, out);
}

// Round 2
// 795.193 us; speedup vs baseline: 1.4103x; 1.4103x over previous
//
#include <hip/hip_runtime.h>

#define NN 50000
#define NE 800000
#define NG 128
#define IN_DIM 12
#define C 64
#define NEG_SLOPE 0.01f

__device__ __forceinline__ float lrelu(float v) {
    return v > 0.f ? v : NEG_SLOPE * v;
}

// h[n][c] = leaky_relu( concat(state,action)[n] @ W_in + b_in )   one wave per node
__global__ void readin_kernel(const float* __restrict__ state,
                              const float* __restrict__ action,
                              const float* __restrict__ W_in,
                              const float* __restrict__ b_in,
                              float* __restrict__ h) {
    __shared__ float sW[IN_DIM * C];
    __shared__ float sb[C];
    int tid = threadIdx.x;
    for (int i = tid; i < IN_DIM * C; i += blockDim.x) sW[i] = W_in[i];
    if (tid < C) sb[tid] = b_in[tid];
    __syncthreads();

    int node = blockIdx.x * (blockDim.x >> 6) + (tid >> 6);
    int c = tid & 63;
    if (node >= NN) return;

    float x[IN_DIM];
#pragma unroll
    for (int k = 0; k < 8; k++) x[k] = state[node * 8 + k];
#pragma unroll
    for (int k = 0; k < 4; k++) x[8 + k] = action[node * 4 + k];

    float acc = sb[c];
#pragma unroll
    for (int k = 0; k < IN_DIM; k++) acc += x[k] * sW[k * C + c];
    h[node * C + c] = lrelu(acc);
}

// agg_e[dst[e]][k] += edge_attr[e][k]   (layer-invariant, done once)
__global__ void scatter_ea_kernel(const int* __restrict__ dst,
                                  const float* __restrict__ edge_attr,
                                  float* __restrict__ agg_e) {
    int idx = blockIdx.x * blockDim.x + threadIdx.x;
    int e = idx >> 4, k = idx & 15;
    if (e >= NE || k >= IN_DIM) return;
    atomicAdd(&agg_e[dst[e] * IN_DIM + k], edge_attr[e * IN_DIM + k]);
}

// agg_h[dst[e]][c] += h[src[e]][c]   one wave per edge, lane = channel
__global__ void scatter_h_kernel(const int* __restrict__ src,
                                 const int* __restrict__ dst,
                                 const float* __restrict__ h,
                                 float* __restrict__ agg) {
    int wid = (blockIdx.x * blockDim.x + threadIdx.x) >> 6;
    int lane = threadIdx.x & 63;
    if (wid >= NE) return;
    int s = src[wid];
    int d = dst[wid];
    atomicAdd(&agg[d * C + lane], h[s * C + lane]);
}

// h_out = leaky_relu( h @ W_self + agg_h @ W_nbr + agg_e @ W_edge + b_conv )
__global__ void node_update_kernel(const float* __restrict__ h,
                                   const float* __restrict__ agg_h,
                                   const float* __restrict__ agg_e,
                                   const float* __restrict__ W_self,
                                   const float* __restrict__ W_nbr,
                                   const float* __restrict__ W_edge,
                                   const float* __restrict__ b_conv,
                                   float* __restrict__ h_out) {
    __shared__ float sWs[C * C];
    __shared__ float sWn[C * C];
    __shared__ float sWe[IN_DIM * C];
    __shared__ float sb[C];
    int tid = threadIdx.x;
    for (int i = tid; i < C * C; i += blockDim.x) {
        sWs[i] = W_self[i];
        sWn[i] = W_nbr[i];
    }
    for (int i = tid; i < IN_DIM * C; i += blockDim.x) sWe[i] = W_edge[i];
    if (tid < C) sb[tid] = b_conv[tid];
    __syncthreads();

    int node = blockIdx.x * (blockDim.x >> 6) + (tid >> 6);
    int c = tid & 63;
    if (node >= NN) return;

    float hv = h[node * C + c];
    float av = agg_h[node * C + c];
    float ev = (c < IN_DIM) ? agg_e[node * IN_DIM + c] : 0.f;

    float acc = sb[c];
#pragma unroll
    for (int k = 0; k < C; k++) {
        float hk = __shfl(hv, k);
        float ak = __shfl(av, k);
        acc += hk * sWs[k * C + c] + ak * sWn[k * C + c];
    }
#pragma unroll
    for (int k = 0; k < IN_DIM; k++) {
        acc += __shfl(ev, k) * sWe[k * C + c];
    }
    h_out[node * C + c] = lrelu(acc);
}

// Fused readout: wave-per-node y = h@W_out + b_out, LDS per-block graph
// partials (batch is sorted -> ~1-2 distinct graphs per block), then a few
// global atomics per block. Avoids 100K same-address global atomics.
__global__ void readout_fused(const float* __restrict__ h,
                              const float* __restrict__ W_out,
                              const float* __restrict__ b_out,
                              const int* __restrict__ batch,
                              float* __restrict__ sums,
                              float* __restrict__ counts) {
    __shared__ float s_sum[NG];
    __shared__ float s_cnt[NG];
    int tid = threadIdx.x;
    if (tid < NG) { s_sum[tid] = 0.f; s_cnt[tid] = 0.f; }
    __syncthreads();

    int lane = tid & 63;
    int wave = tid >> 6;
    int base = blockIdx.x * 256 + wave * 64;   // 64 consecutive nodes per wave
    float w = W_out[lane];
    float b0 = b_out[0];

    float y_local = 0.f;
    for (int i = 0; i < 64; i++) {
        int node = base + i;
        float v = 0.f;
        if (node < NN) v = h[node * C + lane] * w;  // coalesced 256B row
#pragma unroll
        for (int off = 32; off; off >>= 1) v += __shfl_xor(v, off);
        if (lane == i) y_local = v + b0;            // lane i keeps node base+i's y
    }
    int node_l = base + lane;
    if (node_l < NN) {
        int g = batch[node_l];
        atomicAdd(&s_sum[g], y_local);
        atomicAdd(&s_cnt[g], 1.0f);
    }
    __syncthreads();
    if (tid < NG && s_cnt[tid] != 0.f) {
        atomicAdd(&sums[tid], s_sum[tid]);
        atomicAdd(&counts[tid], s_cnt[tid]);
    }
}

__global__ void finalize_kernel(const float* __restrict__ sums,
                                const float* __restrict__ counts,
                                float* __restrict__ out) {
    int g = threadIdx.x;
    if (g < NG) out[g] = sums[g] / fmaxf(counts[g], 1.0f);
}

extern "C" void kernel_launch(void* const* d_in, const int* in_sizes, int n_in,
                              void* d_out, int out_size, void* d_ws, size_t ws_size,
                              hipStream_t stream) {
    const float* state     = (const float*)d_in[0];
    const float* action    = (const float*)d_in[1];
    const int*   edge_index= (const int*)d_in[2];
    const float* edge_attr = (const float*)d_in[3];
    const int*   batch     = (const int*)d_in[4];
    const float* W_in      = (const float*)d_in[5];
    const float* b_in      = (const float*)d_in[6];
    const float* W_self    = (const float*)d_in[7];
    const float* W_nbr     = (const float*)d_in[8];
    const float* W_edge    = (const float*)d_in[9];
    const float* b_conv    = (const float*)d_in[10];
    const float* W_out     = (const float*)d_in[11];
    const float* b_out     = (const float*)d_in[12];
    float* out = (float*)d_out;

    const int* src = edge_index;        // edge_index[0,:]
    const int* dst = edge_index + NE;   // edge_index[1,:]

    // workspace layout (floats)
    float* ws    = (float*)d_ws;
    float* h0    = ws;                  // NN*C
    float* h1    = h0 + NN * C;         // NN*C
    float* agg_h = h1 + NN * C;         // NN*C
    float* agg_e = agg_h + NN * C;      // NN*IN_DIM
    float* sums  = agg_e + NN * IN_DIM; // NG
    float* counts= sums + NG;           // NG

    hipMemsetAsync(agg_e, 0, NN * IN_DIM * sizeof(float), stream);
    hipMemsetAsync(sums, 0, 2 * NG * sizeof(float), stream);

    const int THREADS = 256;
    const int NODES_PER_BLK = THREADS / 64;
    int node_blocks = (NN + NODES_PER_BLK - 1) / NODES_PER_BLK;
    int edge_blocks = (NE + NODES_PER_BLK - 1) / NODES_PER_BLK;

    readin_kernel<<<node_blocks, THREADS, 0, stream>>>(state, action, W_in, b_in, h0);

    int ea_blocks = (NE * 16 + THREADS - 1) / THREADS;
    scatter_ea_kernel<<<ea_blocks, THREADS, 0, stream>>>(dst, edge_attr, agg_e);

    // layer 0
    hipMemsetAsync(agg_h, 0, NN * C * sizeof(float), stream);
    scatter_h_kernel<<<edge_blocks, THREADS, 0, stream>>>(src, dst, h0, agg_h);
    node_update_kernel<<<node_blocks, THREADS, 0, stream>>>(
        h0, agg_h, agg_e,
        W_self, W_nbr, W_edge, b_conv, h1);

    // layer 1
    hipMemsetAsync(agg_h, 0, NN * C * sizeof(float), stream);
    scatter_h_kernel<<<edge_blocks, THREADS, 0, stream>>>(src, dst, h1, agg_h);
    node_update_kernel<<<node_blocks, THREADS, 0, stream>>>(
        h1, agg_h, agg_e,
        W_self + C * C, W_nbr + C * C, W_edge + IN_DIM * C, b_conv + C, h0);

    // fused read-out
    int ro_blocks = (NN + 255) / 256;
    readout_fused<<<ro_blocks, THREADS, 0, stream>>>(h0, W_out, b_out, batch, sums, counts);
    finalize_kernel<<<1, 128, 0, stream>>>(sums, counts, out);
}

// Round 3
// 571.185 us; speedup vs baseline: 1.9634x; 1.3922x over previous
//
#include <hip/hip_runtime.h>

#define NN 50000
#define NE 800000
#define NG 128
#define IN_DIM 12
#define C 64
#define NEG_SLOPE 0.01f
#define SCAN_BLOCKS 196   // ceil(NN/256)

__device__ __forceinline__ float lrelu(float v) {
    return v > 0.f ? v : NEG_SLOPE * v;
}

// ---------------- read-in ----------------
__global__ void readin_kernel(const float* __restrict__ state,
                              const float* __restrict__ action,
                              const float* __restrict__ W_in,
                              const float* __restrict__ b_in,
                              float* __restrict__ h) {
    __shared__ float sW[IN_DIM * C];
    __shared__ float sb[C];
    int tid = threadIdx.x;
    for (int i = tid; i < IN_DIM * C; i += blockDim.x) sW[i] = W_in[i];
    if (tid < C) sb[tid] = b_in[tid];
    __syncthreads();

    int node = blockIdx.x * (blockDim.x >> 6) + (tid >> 6);
    int c = tid & 63;
    if (node >= NN) return;

    float x[IN_DIM];
#pragma unroll
    for (int k = 0; k < 8; k++) x[k] = state[node * 8 + k];
#pragma unroll
    for (int k = 0; k < 4; k++) x[8 + k] = action[node * 4 + k];

    float acc = sb[c];
#pragma unroll
    for (int k = 0; k < IN_DIM; k++) acc += x[k] * sW[k * C + c];
    h[node * C + c] = lrelu(acc);
}

// ---------------- CSR build ----------------
__global__ void hist_kernel(const int* __restrict__ dst, int* __restrict__ deg) {
    int e = blockIdx.x * blockDim.x + threadIdx.x;
    if (e < NE) atomicAdd(&deg[dst[e]], 1);
}

// block-level inclusive scan -> exclusive per-element + block totals
__global__ void scan1_kernel(const int* __restrict__ deg,
                             int* __restrict__ excl,
                             int* __restrict__ bsum) {
    __shared__ int tmp[256];
    int tid = threadIdx.x;
    int i = blockIdx.x * 256 + tid;
    int v = (i < NN) ? deg[i] : 0;
    tmp[tid] = v;
    __syncthreads();
    for (int off = 1; off < 256; off <<= 1) {
        int t = (tid >= off) ? tmp[tid - off] : 0;
        __syncthreads();
        tmp[tid] += t;
        __syncthreads();
    }
    if (i < NN) excl[i] = tmp[tid] - v;
    if (tid == 255) bsum[blockIdx.x] = tmp[255];
}

__global__ void scan2_kernel(int* __restrict__ bsum, int* __restrict__ bexcl) {
    __shared__ int tmp[256];
    int tid = threadIdx.x;
    int v = (tid < SCAN_BLOCKS) ? bsum[tid] : 0;
    tmp[tid] = v;
    __syncthreads();
    for (int off = 1; off < 256; off <<= 1) {
        int t = (tid >= off) ? tmp[tid - off] : 0;
        __syncthreads();
        tmp[tid] += t;
        __syncthreads();
    }
    if (tid < SCAN_BLOCKS) bexcl[tid] = tmp[tid] - v;
}

// row_start = excl + block offset; cursor = copy
__global__ void scan3_kernel(const int* __restrict__ excl,
                             const int* __restrict__ bexcl,
                             int* __restrict__ row_start,
                             int* __restrict__ cursor) {
    int i = blockIdx.x * 256 + threadIdx.x;
    if (i >= NN) return;
    int v = excl[i] + bexcl[blockIdx.x];
    row_start[i] = v;
    cursor[i] = v;
}

__global__ void fill_kernel(const int* __restrict__ src,
                            const int* __restrict__ dst,
                            int* __restrict__ cursor,
                            int* __restrict__ csr_src,
                            int* __restrict__ csr_eid) {
    int e = blockIdx.x * blockDim.x + threadIdx.x;
    if (e >= NE) return;
    int d = dst[e];
    int slot = atomicAdd(&cursor[d], 1);
    csr_src[slot] = src[e];
    csr_eid[slot] = e;
}

// agg_e[n][k] = sum over incoming edges of edge_attr[e][k]  (gather, once)
__global__ void agg_e_gather(const float* __restrict__ edge_attr,
                             const int* __restrict__ row_start,
                             const int* __restrict__ deg,
                             const int* __restrict__ csr_eid,
                             float* __restrict__ agg_e) {
    int tid = threadIdx.x;
    int node = blockIdx.x * (blockDim.x >> 6) + (tid >> 6);
    int lane = tid & 63;
    int g = lane >> 4;        // 4 edge groups
    int c = lane & 15;        // channel within group (only c<12 used)
    if (node >= NN) return;
    int start = row_start[node], cnt = deg[node];
    float acc = 0.f;
    for (int i = g; i < cnt; i += 4) {
        int e = csr_eid[start + i];
        if (c < IN_DIM) acc += edge_attr[e * IN_DIM + c];
    }
    acc += __shfl_xor(acc, 16);
    acc += __shfl_xor(acc, 32);
    if (lane < IN_DIM) agg_e[node * IN_DIM + lane] = acc;
}

// Fused: gather agg_h over incoming edges + node update, wave per node
__global__ void layer_kernel(const float* __restrict__ h_in,
                             const int* __restrict__ row_start,
                             const int* __restrict__ deg,
                             const int* __restrict__ csr_src,
                             const float* __restrict__ agg_e,
                             const float* __restrict__ W_self,
                             const float* __restrict__ W_nbr,
                             const float* __restrict__ W_edge,
                             const float* __restrict__ b_conv,
                             float* __restrict__ h_out) {
    __shared__ float sWs[C * C];
    __shared__ float sWn[C * C];
    __shared__ float sWe[IN_DIM * C];
    __shared__ float sb[C];
    int tid = threadIdx.x;
    for (int i = tid; i < C * C; i += blockDim.x) {
        sWs[i] = W_self[i];
        sWn[i] = W_nbr[i];
    }
    for (int i = tid; i < IN_DIM * C; i += blockDim.x) sWe[i] = W_edge[i];
    if (tid < C) sb[tid] = b_conv[tid];
    __syncthreads();

    int node = blockIdx.x * (blockDim.x >> 6) + (tid >> 6);
    int c = tid & 63;
    if (node >= NN) return;

    int start = row_start[node], cnt = deg[node];
    float agg = 0.f;
    int i = 0;
    for (; i + 4 <= cnt; i += 4) {
        int s0 = csr_src[start + i];
        int s1 = csr_src[start + i + 1];
        int s2 = csr_src[start + i + 2];
        int s3 = csr_src[start + i + 3];
        float a0 = h_in[s0 * C + c];
        float a1 = h_in[s1 * C + c];
        float a2 = h_in[s2 * C + c];
        float a3 = h_in[s3 * C + c];
        agg += (a0 + a1) + (a2 + a3);
    }
    for (; i < cnt; i++) agg += h_in[csr_src[start + i] * C + c];

    float hv = h_in[node * C + c];
    float ev = (c < IN_DIM) ? agg_e[node * IN_DIM + c] : 0.f;

    float acc = sb[c];
#pragma unroll
    for (int k = 0; k < C; k++) {
        acc += __shfl(hv, k) * sWs[k * C + c] + __shfl(agg, k) * sWn[k * C + c];
    }
#pragma unroll
    for (int k = 0; k < IN_DIM; k++) {
        acc += __shfl(ev, k) * sWe[k * C + c];
    }
    h_out[node * C + c] = lrelu(acc);
}

// ---------------- read-out ----------------
__global__ void readout_fused(const float* __restrict__ h,
                              const float* __restrict__ W_out,
                              const float* __restrict__ b_out,
                              const int* __restrict__ batch,
                              float* __restrict__ sums,
                              float* __restrict__ counts) {
    __shared__ float s_sum[NG];
    __shared__ float s_cnt[NG];
    int tid = threadIdx.x;
    if (tid < NG) { s_sum[tid] = 0.f; s_cnt[tid] = 0.f; }
    __syncthreads();

    int lane = tid & 63;
    int wave = tid >> 6;
    int base = blockIdx.x * 256 + wave * 64;
    float w = W_out[lane];
    float b0 = b_out[0];

    float y_local = 0.f;
    for (int i = 0; i < 64; i++) {
        int node = base + i;
        float v = 0.f;
        if (node < NN) v = h[node * C + lane] * w;
#pragma unroll
        for (int off = 32; off; off >>= 1) v += __shfl_xor(v, off);
        if (lane == i) y_local = v + b0;
    }
    int node_l = base + lane;
    if (node_l < NN) {
        int g = batch[node_l];
        atomicAdd(&s_sum[g], y_local);
        atomicAdd(&s_cnt[g], 1.0f);
    }
    __syncthreads();
    if (tid < NG && s_cnt[tid] != 0.f) {
        atomicAdd(&sums[tid], s_sum[tid]);
        atomicAdd(&counts[tid], s_cnt[tid]);
    }
}

__global__ void finalize_kernel(const float* __restrict__ sums,
                                const float* __restrict__ counts,
                                float* __restrict__ out) {
    int g = threadIdx.x;
    if (g < NG) out[g] = sums[g] / fmaxf(counts[g], 1.0f);
}

extern "C" void kernel_launch(void* const* d_in, const int* in_sizes, int n_in,
                              void* d_out, int out_size, void* d_ws, size_t ws_size,
                              hipStream_t stream) {
    const float* state     = (const float*)d_in[0];
    const float* action    = (const float*)d_in[1];
    const int*   edge_index= (const int*)d_in[2];
    const float* edge_attr = (const float*)d_in[3];
    const int*   batch     = (const int*)d_in[4];
    const float* W_in      = (const float*)d_in[5];
    const float* b_in      = (const float*)d_in[6];
    const float* W_self    = (const float*)d_in[7];
    const float* W_nbr     = (const float*)d_in[8];
    const float* W_edge    = (const float*)d_in[9];
    const float* b_conv    = (const float*)d_in[10];
    const float* W_out     = (const float*)d_in[11];
    const float* b_out     = (const float*)d_in[12];
    float* out = (float*)d_out;

    const int* src = edge_index;        // edge_index[0,:]
    const int* dst = edge_index + NE;   // edge_index[1,:]

    // workspace layout (4-byte elements)
    float* ws      = (float*)d_ws;
    float* h0      = ws;                      // NN*C
    float* h1      = h0 + NN * C;             // NN*C
    float* agg_e   = h1 + NN * C;             // NN*IN_DIM
    float* sums    = agg_e + NN * IN_DIM;     // NG
    float* counts  = sums + NG;               // NG
    int*   deg     = (int*)(counts + NG);     // NN
    int*   excl    = deg + NN;                // NN
    int*   row_start = excl + NN;             // NN
    int*   cursor  = row_start + NN;          // NN
    int*   bsum    = cursor + NN;             // 256
    int*   bexcl   = bsum + 256;              // 256
    int*   csr_src = bexcl + 256;             // NE
    int*   csr_eid = csr_src + NE;            // NE

    hipMemsetAsync(deg, 0, NN * sizeof(int), stream);
    hipMemsetAsync(sums, 0, 2 * NG * sizeof(float), stream);

    const int THREADS = 256;
    const int NPB = THREADS / 64;                       // nodes per block
    int node_blocks = (NN + NPB - 1) / NPB;             // 12500
    int edge_tblocks = (NE + THREADS - 1) / THREADS;    // 3125

    // read-in (independent of CSR build)
    readin_kernel<<<node_blocks, THREADS, 0, stream>>>(state, action, W_in, b_in, h0);

    // CSR build
    hist_kernel<<<edge_tblocks, THREADS, 0, stream>>>(dst, deg);
    scan1_kernel<<<SCAN_BLOCKS, 256, 0, stream>>>(deg, excl, bsum);
    scan2_kernel<<<1, 256, 0, stream>>>(bsum, bexcl);
    scan3_kernel<<<SCAN_BLOCKS, 256, 0, stream>>>(excl, bexcl, row_start, cursor);
    fill_kernel<<<edge_tblocks, THREADS, 0, stream>>>(src, dst, cursor, csr_src, csr_eid);

    // layer-invariant edge_attr aggregation (gather)
    agg_e_gather<<<node_blocks, THREADS, 0, stream>>>(edge_attr, row_start, deg, csr_eid, agg_e);

    // layer 0: h0 -> h1
    layer_kernel<<<node_blocks, THREADS, 0, stream>>>(
        h0, row_start, deg, csr_src, agg_e,
        W_self, W_nbr, W_edge, b_conv, h1);

    // layer 1: h1 -> h0
    layer_kernel<<<node_blocks, THREADS, 0, stream>>>(
        h1, row_start, deg, csr_src, agg_e,
        W_self + C * C, W_nbr + C * C, W_edge + IN_DIM * C, b_conv + C, h0);

    // read-out
    int ro_blocks = (NN + 255) / 256;
    readout_fused<<<ro_blocks, THREADS, 0, stream>>>(h0, W_out, b_out, batch, sums, counts);
    finalize_kernel<<<1, 128, 0, stream>>>(sums, counts, out);
}

// Round 4
// 512.955 us; speedup vs baseline: 2.1863x; 1.1135x over previous
//
#include <hip/hip_runtime.h>

#define NN 50000
#define NE 800000
#define NG 128
#define IN_DIM 12
#define C 64
#define NEG_SLOPE 0.01f
#define SCAN_BLOCKS 196   // ceil(NN/256)

__device__ __forceinline__ float lrelu(float v) {
    return v > 0.f ? v : NEG_SLOPE * v;
}

__device__ __forceinline__ float bflo(uint32_t v) { return __uint_as_float(v << 16); }
__device__ __forceinline__ float bfhi(uint32_t v) { return __uint_as_float(v & 0xffff0000u); }
// pack two f32 -> bf16 pair (RNE), lo in low 16 bits
__device__ __forceinline__ uint32_t pack_bf16(float lo, float hi) {
    uint32_t a = __float_as_uint(lo); a += 0x7fffu + ((a >> 16) & 1u);
    uint32_t b = __float_as_uint(hi); b += 0x7fffu + ((b >> 16) & 1u);
    return (a >> 16) | (b & 0xffff0000u ? ((b >> 16) << 16) : ((b >> 16) << 16));
}

// ---------------- read-in ----------------
// h f32 [NN][C] plus bf16 packed copy hb [NN][32] (channels 2q,2q+1 per uint)
__global__ void readin_kernel(const float* __restrict__ state,
                              const float* __restrict__ action,
                              const float* __restrict__ W_in,
                              const float* __restrict__ b_in,
                              float* __restrict__ h,
                              uint32_t* __restrict__ hb) {
    __shared__ float sW[IN_DIM * C];
    __shared__ float sb[C];
    int tid = threadIdx.x;
    for (int i = tid; i < IN_DIM * C; i += blockDim.x) sW[i] = W_in[i];
    if (tid < C) sb[tid] = b_in[tid];
    __syncthreads();

    int node = blockIdx.x * (blockDim.x >> 6) + (tid >> 6);
    int c = tid & 63;
    if (node >= NN) return;

    float x[IN_DIM];
#pragma unroll
    for (int k = 0; k < 8; k++) x[k] = state[node * 8 + k];
#pragma unroll
    for (int k = 0; k < 4; k++) x[8 + k] = action[node * 4 + k];

    float acc = sb[c];
#pragma unroll
    for (int k = 0; k < IN_DIM; k++) acc += x[k] * sW[k * C + c];
    float res = lrelu(acc);
    h[node * C + c] = res;
    float p = __shfl_xor(res, 1);
    if (!(c & 1)) hb[node * 32 + (c >> 1)] = pack_bf16(res, p);
}

// ---------------- CSR build ----------------
__global__ void hist_kernel(const int* __restrict__ dst, int* __restrict__ deg) {
    int e = blockIdx.x * blockDim.x + threadIdx.x;
    if (e < NE) atomicAdd(&deg[dst[e]], 1);
}

__global__ void scan1_kernel(const int* __restrict__ deg,
                             int* __restrict__ excl,
                             int* __restrict__ bsum) {
    __shared__ int tmp[256];
    int tid = threadIdx.x;
    int i = blockIdx.x * 256 + tid;
    int v = (i < NN) ? deg[i] : 0;
    tmp[tid] = v;
    __syncthreads();
    for (int off = 1; off < 256; off <<= 1) {
        int t = (tid >= off) ? tmp[tid - off] : 0;
        __syncthreads();
        tmp[tid] += t;
        __syncthreads();
    }
    if (i < NN) excl[i] = tmp[tid] - v;
    if (tid == 255) bsum[blockIdx.x] = tmp[255];
}

__global__ void scan2_kernel(int* __restrict__ bsum, int* __restrict__ bexcl) {
    __shared__ int tmp[256];
    int tid = threadIdx.x;
    int v = (tid < SCAN_BLOCKS) ? bsum[tid] : 0;
    tmp[tid] = v;
    __syncthreads();
    for (int off = 1; off < 256; off <<= 1) {
        int t = (tid >= off) ? tmp[tid - off] : 0;
        __syncthreads();
        tmp[tid] += t;
        __syncthreads();
    }
    if (tid < SCAN_BLOCKS) bexcl[tid] = tmp[tid] - v;
}

__global__ void scan3_kernel(const int* __restrict__ excl,
                             const int* __restrict__ bexcl,
                             int* __restrict__ row_start,
                             int* __restrict__ cursor) {
    int i = blockIdx.x * 256 + threadIdx.x;
    if (i >= NN) return;
    int v = excl[i] + bexcl[blockIdx.x];
    row_start[i] = v;
    cursor[i] = v;
}

__global__ void fill_kernel(const int* __restrict__ src,
                            const int* __restrict__ dst,
                            int* __restrict__ cursor,
                            int* __restrict__ csr_src,
                            int* __restrict__ csr_eid) {
    int e = blockIdx.x * blockDim.x + threadIdx.x;
    if (e >= NE) return;
    int d = dst[e];
    int slot = atomicAdd(&cursor[d], 1);
    csr_src[slot] = src[e];
    csr_eid[slot] = e;
}

// agg_e[n][k] = sum of edge_attr over incoming edges (gather, once)
__global__ void agg_e_gather(const float* __restrict__ edge_attr,
                             const int* __restrict__ row_start,
                             const int* __restrict__ deg,
                             const int* __restrict__ csr_eid,
                             float* __restrict__ agg_e) {
    int tid = threadIdx.x;
    int node = blockIdx.x * (blockDim.x >> 6) + (tid >> 6);
    int lane = tid & 63;
    int g = lane >> 4;
    int c = lane & 15;
    if (node >= NN) return;
    int start = row_start[node], cnt = deg[node];
    float acc = 0.f;
    for (int i = g; i < cnt; i += 4) {
        int e = csr_eid[start + i];
        if (c < IN_DIM) acc += edge_attr[e * IN_DIM + c];
    }
    acc += __shfl_xor(acc, 16);
    acc += __shfl_xor(acc, 32);
    if (lane < IN_DIM) agg_e[node * IN_DIM + lane] = acc;
}

// Fused: bf16 gather of neighbor sum + f32 node update. Wave per node,
// 512-thread blocks (8 waves share the 36KB weight LDS -> ~100% occupancy).
__global__ void layer_kernel(const float* __restrict__ h_in,
                             const uint32_t* __restrict__ hb_in,
                             const int* __restrict__ row_start,
                             const int* __restrict__ deg,
                             const int* __restrict__ csr_src,
                             const float* __restrict__ agg_e,
                             const float* __restrict__ W_self,
                             const float* __restrict__ W_nbr,
                             const float* __restrict__ W_edge,
                             const float* __restrict__ b_conv,
                             float* __restrict__ h_out,
                             uint32_t* __restrict__ hb_out,
                             int write_bf16) {
    __shared__ float sWs[C * C];
    __shared__ float sWn[C * C];
    __shared__ float sWe[IN_DIM * C];
    __shared__ float sb[C];
    int tid = threadIdx.x;
    for (int i = tid; i < C * C; i += blockDim.x) {
        sWs[i] = W_self[i];
        sWn[i] = W_nbr[i];
    }
    for (int i = tid; i < IN_DIM * C; i += blockDim.x) sWe[i] = W_edge[i];
    if (tid < C) sb[tid] = b_conv[tid];
    __syncthreads();

    int node = blockIdx.x * (blockDim.x >> 6) + (tid >> 6);
    int c = tid & 63;
    if (node >= NN) return;

    int start = row_start[node], cnt = deg[node];
    int half = c >> 5;        // lanes 0-31: even edges, 32-63: odd edges
    int q = c & 31;           // uint column (channels 2q, 2q+1)

    float a0 = 0.f, a1 = 0.f;
    int i = 0;
    for (; i + 4 <= cnt; i += 4) {
        int s0 = csr_src[start + i + half];
        int s1 = csr_src[start + i + 2 + half];
        uint32_t v0 = hb_in[s0 * 32 + q];
        uint32_t v1 = hb_in[s1 * 32 + q];
        a0 += bflo(v0); a1 += bfhi(v0);
        a0 += bflo(v1); a1 += bfhi(v1);
    }
    for (; i + 2 <= cnt; i += 2) {
        int s = csr_src[start + i + half];
        uint32_t v = hb_in[s * 32 + q];
        a0 += bflo(v); a1 += bfhi(v);
    }
    if (i < cnt && half == 0) {     // odd tail edge
        int s = csr_src[start + i];
        uint32_t v = hb_in[s * 32 + q];
        a0 += bflo(v); a1 += bfhi(v);
    }
    // combine the two edge halves, then redistribute pair layout -> lane=c
    a0 += __shfl_xor(a0, 32);
    a1 += __shfl_xor(a1, 32);
    float t0 = __shfl(a0, c >> 1);
    float t1 = __shfl(a1, c >> 1);
    float agg = (c & 1) ? t1 : t0;

    float hv = h_in[node * C + c];
    float ev = (c < IN_DIM) ? agg_e[node * IN_DIM + c] : 0.f;

    float acc = sb[c];
#pragma unroll
    for (int k = 0; k < C; k++) {
        acc += __shfl(hv, k) * sWs[k * C + c] + __shfl(agg, k) * sWn[k * C + c];
    }
#pragma unroll
    for (int k = 0; k < IN_DIM; k++) {
        acc += __shfl(ev, k) * sWe[k * C + c];
    }
    float res = lrelu(acc);
    h_out[node * C + c] = res;
    if (write_bf16) {
        float p = __shfl_xor(res, 1);
        if (!(c & 1)) hb_out[node * 32 + (c >> 1)] = pack_bf16(res, p);
    }
}

// ---------------- read-out ----------------
__global__ void readout_fused(const float* __restrict__ h,
                              const float* __restrict__ W_out,
                              const float* __restrict__ b_out,
                              const int* __restrict__ batch,
                              float* __restrict__ sums,
                              float* __restrict__ counts) {
    __shared__ float s_sum[NG];
    __shared__ float s_cnt[NG];
    int tid = threadIdx.x;
    if (tid < NG) { s_sum[tid] = 0.f; s_cnt[tid] = 0.f; }
    __syncthreads();

    int lane = tid & 63;
    int wave = tid >> 6;
    int base = blockIdx.x * 256 + wave * 64;
    float w = W_out[lane];
    float b0 = b_out[0];

    float y_local = 0.f;
    for (int i = 0; i < 64; i++) {
        int node = base + i;
        float v = 0.f;
        if (node < NN) v = h[node * C + lane] * w;
#pragma unroll
        for (int off = 32; off; off >>= 1) v += __shfl_xor(v, off);
        if (lane == i) y_local = v + b0;
    }
    int node_l = base + lane;
    if (node_l < NN) {
        int g = batch[node_l];
        atomicAdd(&s_sum[g], y_local);
        atomicAdd(&s_cnt[g], 1.0f);
    }
    __syncthreads();
    if (tid < NG && s_cnt[tid] != 0.f) {
        atomicAdd(&sums[tid], s_sum[tid]);
        atomicAdd(&counts[tid], s_cnt[tid]);
    }
}

__global__ void finalize_kernel(const float* __restrict__ sums,
                                const float* __restrict__ counts,
                                float* __restrict__ out) {
    int g = threadIdx.x;
    if (g < NG) out[g] = sums[g] / fmaxf(counts[g], 1.0f);
}

extern "C" void kernel_launch(void* const* d_in, const int* in_sizes, int n_in,
                              void* d_out, int out_size, void* d_ws, size_t ws_size,
                              hipStream_t stream) {
    const float* state     = (const float*)d_in[0];
    const float* action    = (const float*)d_in[1];
    const int*   edge_index= (const int*)d_in[2];
    const float* edge_attr = (const float*)d_in[3];
    const int*   batch     = (const int*)d_in[4];
    const float* W_in      = (const float*)d_in[5];
    const float* b_in      = (const float*)d_in[6];
    const float* W_self    = (const float*)d_in[7];
    const float* W_nbr     = (const float*)d_in[8];
    const float* W_edge    = (const float*)d_in[9];
    const float* b_conv    = (const float*)d_in[10];
    const float* W_out     = (const float*)d_in[11];
    const float* b_out     = (const float*)d_in[12];
    float* out = (float*)d_out;

    const int* src = edge_index;        // edge_index[0,:]
    const int* dst = edge_index + NE;   // edge_index[1,:]

    // workspace layout (4-byte elements)
    float* ws      = (float*)d_ws;
    float* h0      = ws;                      // NN*C
    float* h1      = h0 + NN * C;             // NN*C
    float* agg_e   = h1 + NN * C;             // NN*IN_DIM
    float* sums    = agg_e + NN * IN_DIM;     // NG
    float* counts  = sums + NG;               // NG
    int*   deg     = (int*)(counts + NG);     // NN
    int*   excl    = deg + NN;                // NN
    int*   row_start = excl + NN;             // NN
    int*   cursor  = row_start + NN;          // NN
    int*   bsum    = cursor + NN;             // 256
    int*   bexcl   = bsum + 256;              // 256
    int*   csr_src = bexcl + 256;             // NE
    int*   csr_eid = csr_src + NE;            // NE
    uint32_t* hb0  = (uint32_t*)(csr_eid + NE); // NN*32
    uint32_t* hb1  = hb0 + NN * 32;             // NN*32

    hipMemsetAsync(deg, 0, NN * sizeof(int), stream);
    hipMemsetAsync(sums, 0, 2 * NG * sizeof(float), stream);

    const int THREADS = 256;
    int node_blocks = (NN + 3) / 4;                     // 256-thr kernels
    int edge_tblocks = (NE + THREADS - 1) / THREADS;

    readin_kernel<<<node_blocks, THREADS, 0, stream>>>(state, action, W_in, b_in, h0, hb0);

    hist_kernel<<<edge_tblocks, THREADS, 0, stream>>>(dst, deg);
    scan1_kernel<<<SCAN_BLOCKS, 256, 0, stream>>>(deg, excl, bsum);
    scan2_kernel<<<1, 256, 0, stream>>>(bsum, bexcl);
    scan3_kernel<<<SCAN_BLOCKS, 256, 0, stream>>>(excl, bexcl, row_start, cursor);
    fill_kernel<<<edge_tblocks, THREADS, 0, stream>>>(src, dst, cursor, csr_src, csr_eid);

    agg_e_gather<<<node_blocks, THREADS, 0, stream>>>(edge_attr, row_start, deg, csr_eid, agg_e);

    // layers: 512-thread blocks, 8 nodes per block
    int layer_blocks = (NN + 7) / 8;
    layer_kernel<<<layer_blocks, 512, 0, stream>>>(
        h0, hb0, row_start, deg, csr_src, agg_e,
        W_self, W_nbr, W_edge, b_conv, h1, hb1, 1);
    layer_kernel<<<layer_blocks, 512, 0, stream>>>(
        h1, hb1, row_start, deg, csr_src, agg_e,
        W_self + C * C, W_nbr + C * C, W_edge + IN_DIM * C, b_conv + C, h0, hb0, 0);

    int ro_blocks = (NN + 255) / 256;
    readout_fused<<<ro_blocks, THREADS, 0, stream>>>(h0, W_out, b_out, batch, sums, counts);
    finalize_kernel<<<1, 128, 0, stream>>>(sums, counts, out);
}

// Round 5
// 495.263 us; speedup vs baseline: 2.2644x; 1.0357x over previous
//
#include <hip/hip_runtime.h>

#define NN 50000
#define NE 800000
#define NG 128
#define IN_DIM 12
#define C 64
#define NEG_SLOPE 0.01f
#define SCAN_BLOCKS 196   // ceil(NN/256)

__device__ __forceinline__ float lrelu(float v) {
    return v > 0.f ? v : NEG_SLOPE * v;
}

__device__ __forceinline__ float bflo(uint32_t v) { return __uint_as_float(v << 16); }
__device__ __forceinline__ float bfhi(uint32_t v) { return __uint_as_float(v & 0xffff0000u); }
// pack two f32 -> bf16 pair (RNE), lo in low 16 bits
__device__ __forceinline__ uint32_t pack_bf16(float lo, float hi) {
    uint32_t a = __float_as_uint(lo); a += 0x7fffu + ((a >> 16) & 1u);
    uint32_t b = __float_as_uint(hi); b += 0x7fffu + ((b >> 16) & 1u);
    return (a >> 16) | (b & 0xffff0000u);
}

// ---------------- read-in ----------------
__global__ void readin_kernel(const float* __restrict__ state,
                              const float* __restrict__ action,
                              const float* __restrict__ W_in,
                              const float* __restrict__ b_in,
                              float* __restrict__ h,
                              uint32_t* __restrict__ hb) {
    __shared__ float sW[IN_DIM * C];
    __shared__ float sb[C];
    int tid = threadIdx.x;
    for (int i = tid; i < IN_DIM * C; i += blockDim.x) sW[i] = W_in[i];
    if (tid < C) sb[tid] = b_in[tid];
    __syncthreads();

    int node = blockIdx.x * (blockDim.x >> 6) + (tid >> 6);
    int c = tid & 63;
    if (node >= NN) return;

    float x[IN_DIM];
#pragma unroll
    for (int k = 0; k < 8; k++) x[k] = state[node * 8 + k];
#pragma unroll
    for (int k = 0; k < 4; k++) x[8 + k] = action[node * 4 + k];

    float acc = sb[c];
#pragma unroll
    for (int k = 0; k < IN_DIM; k++) acc += x[k] * sW[k * C + c];
    float res = lrelu(acc);
    h[node * C + c] = res;
    float p = __shfl_xor(res, 1);
    if (!(c & 1)) hb[node * 32 + (c >> 1)] = pack_bf16(res, p);
}

// ---------------- CSR build ----------------
__global__ void hist_kernel(const int* __restrict__ dst, int* __restrict__ deg) {
    int e = blockIdx.x * blockDim.x + threadIdx.x;
    if (e < NE) atomicAdd(&deg[dst[e]], 1);
}

__global__ void scan1_kernel(const int* __restrict__ deg,
                             int* __restrict__ excl,
                             int* __restrict__ bsum) {
    __shared__ int tmp[256];
    int tid = threadIdx.x;
    int i = blockIdx.x * 256 + tid;
    int v = (i < NN) ? deg[i] : 0;
    tmp[tid] = v;
    __syncthreads();
    for (int off = 1; off < 256; off <<= 1) {
        int t = (tid >= off) ? tmp[tid - off] : 0;
        __syncthreads();
        tmp[tid] += t;
        __syncthreads();
    }
    if (i < NN) excl[i] = tmp[tid] - v;
    if (tid == 255) bsum[blockIdx.x] = tmp[255];
}

// fused: block offset from bsum + row_start/cursor write
__global__ void scan23_kernel(const int* __restrict__ excl,
                              const int* __restrict__ bsum,
                              int* __restrict__ row_start,
                              int* __restrict__ cursor) {
    __shared__ int s_off;
    int tid = threadIdx.x;
    if (tid < 64) {
        int p = 0;
        for (int i = tid; i < blockIdx.x; i += 64) p += bsum[i];
#pragma unroll
        for (int off = 32; off; off >>= 1) p += __shfl_xor(p, off);
        if (tid == 0) s_off = p;
    }
    __syncthreads();
    int i = blockIdx.x * 256 + tid;
    if (i < NN) {
        int v = excl[i] + s_off;
        row_start[i] = v;
        cursor[i] = v;
    }
}

__global__ void fill_kernel(const int* __restrict__ src,
                            const int* __restrict__ dst,
                            int* __restrict__ cursor,
                            int* __restrict__ csr_src,
                            int* __restrict__ csr_eid) {
    int e = blockIdx.x * blockDim.x + threadIdx.x;
    if (e >= NE) return;
    int d = dst[e];
    int slot = atomicAdd(&cursor[d], 1);
    csr_src[slot] = src[e];
    csr_eid[slot] = e;
}

// agg_e[n][k] = sum of edge_attr over incoming edges (gather, MLP-friendly)
__global__ void agg_e_gather(const float* __restrict__ edge_attr,
                             const int* __restrict__ row_start,
                             const int* __restrict__ deg,
                             const int* __restrict__ csr_eid,
                             float* __restrict__ agg_e) {
    int tid = threadIdx.x;
    int node = blockIdx.x * (blockDim.x >> 6) + (tid >> 6);
    int lane = tid & 63;
    int g = lane >> 4;        // 4 edge groups of 16 lanes
    int cc = lane & 15;
    if (node >= NN) return;
    int start = row_start[node], cnt = deg[node];

    int myeid = (lane < cnt) ? csr_eid[start + lane] : 0;
    int nb = cnt < 64 ? cnt : 64;

    float acc = 0.f, acc2 = 0.f;
    int j = 0;
    for (; j + 8 <= nb; j += 8) {
        int e0 = __shfl(myeid, j + g);
        int e1 = __shfl(myeid, j + 4 + g);
        if (cc < IN_DIM) {
            acc  += edge_attr[e0 * IN_DIM + cc];
            acc2 += edge_attr[e1 * IN_DIM + cc];
        }
    }
    for (; j + 4 <= nb; j += 4) {
        int e0 = __shfl(myeid, j + g);
        if (cc < IN_DIM) acc += edge_attr[e0 * IN_DIM + cc];
    }
    {   // tail 0..3 edges
        int e0 = __shfl(myeid, (j + g < 64) ? (j + g) : 0);
        if (j + g < nb && cc < IN_DIM) acc += edge_attr[e0 * IN_DIM + cc];
    }
    for (int i2 = 64 + g; i2 < cnt; i2 += 4) {   // rare overflow path
        int e = csr_eid[start + i2];
        if (cc < IN_DIM) acc += edge_attr[e * IN_DIM + cc];
    }
    acc += acc2;
    acc += __shfl_xor(acc, 16);
    acc += __shfl_xor(acc, 32);
    if (lane < IN_DIM) agg_e[node * IN_DIM + lane] = acc;
}

// Fused: bf16 neighbor gather (lane-parallel index prefetch, 8 edges/iter,
// 4 independent loads per half-wave in flight) + f32 node update.
__global__ void layer_kernel(const float* __restrict__ h_in,
                             const uint32_t* __restrict__ hb_in,
                             const int* __restrict__ row_start,
                             const int* __restrict__ deg,
                             const int* __restrict__ csr_src,
                             const float* __restrict__ agg_e,
                             const float* __restrict__ W_self,
                             const float* __restrict__ W_nbr,
                             const float* __restrict__ W_edge,
                             const float* __restrict__ b_conv,
                             float* __restrict__ h_out,
                             uint32_t* __restrict__ hb_out,
                             int write_bf16) {
    __shared__ float sWs[C * C];
    __shared__ float sWn[C * C];
    __shared__ float sWe[IN_DIM * C];
    __shared__ float sb[C];
    int tid = threadIdx.x;
    for (int i = tid; i < C * C; i += blockDim.x) {
        sWs[i] = W_self[i];
        sWn[i] = W_nbr[i];
    }
    for (int i = tid; i < IN_DIM * C; i += blockDim.x) sWe[i] = W_edge[i];
    if (tid < C) sb[tid] = b_conv[tid];
    __syncthreads();

    int node = blockIdx.x * (blockDim.x >> 6) + (tid >> 6);
    int c = tid & 63;
    if (node >= NN) return;

    int start = row_start[node], cnt = deg[node];
    int half = c >> 5;        // lanes 0-31 / 32-63 take different edges
    int q = c & 31;           // uint column (channels 2q, 2q+1)

    // one coalesced load grabs up to 64 neighbor indices
    int myidx = (c < cnt) ? csr_src[start + c] : 0;
    int nb = cnt < 64 ? cnt : 64;

    float a0 = 0.f, a1 = 0.f, b0v = 0.f, b1v = 0.f;
    int j = 0;
    for (; j + 8 <= nb; j += 8) {
        int p = j + 4 * half;
        int s0 = __shfl(myidx, p);
        int s1 = __shfl(myidx, p + 1);
        int s2 = __shfl(myidx, p + 2);
        int s3 = __shfl(myidx, p + 3);
        uint32_t v0 = hb_in[s0 * 32 + q];
        uint32_t v1 = hb_in[s1 * 32 + q];
        uint32_t v2 = hb_in[s2 * 32 + q];
        uint32_t v3 = hb_in[s3 * 32 + q];
        a0  += bflo(v0); a1  += bfhi(v0);
        b0v += bflo(v1); b1v += bfhi(v1);
        a0  += bflo(v2); a1  += bfhi(v2);
        b0v += bflo(v3); b1v += bfhi(v3);
    }
    for (; j + 2 <= nb; j += 2) {
        int s = __shfl(myidx, j + half);
        uint32_t v = hb_in[s * 32 + q];
        a0 += bflo(v); a1 += bfhi(v);
    }
    {   // odd tail edge
        int s = __shfl(myidx, (j < 64) ? j : 0);
        if (j < nb && half == 0) {
            uint32_t v = hb_in[s * 32 + q];
            a0 += bflo(v); a1 += bfhi(v);
        }
    }
    for (int i2 = 64 + half; i2 < cnt; i2 += 2) {   // rare overflow path
        int s = csr_src[start + i2];
        uint32_t v = hb_in[s * 32 + q];
        a0 += bflo(v); a1 += bfhi(v);
    }

    a0 += b0v; a1 += b1v;
    a0 += __shfl_xor(a0, 32);
    a1 += __shfl_xor(a1, 32);
    float t0 = __shfl(a0, c >> 1);
    float t1 = __shfl(a1, c >> 1);
    float agg = (c & 1) ? t1 : t0;

    float hv = h_in[node * C + c];
    float ev = (c < IN_DIM) ? agg_e[node * IN_DIM + c] : 0.f;

    float acc = sb[c];
#pragma unroll
    for (int k = 0; k < C; k++) {
        acc += __shfl(hv, k) * sWs[k * C + c] + __shfl(agg, k) * sWn[k * C + c];
    }
#pragma unroll
    for (int k = 0; k < IN_DIM; k++) {
        acc += __shfl(ev, k) * sWe[k * C + c];
    }
    float res = lrelu(acc);
    h_out[node * C + c] = res;
    if (write_bf16) {
        float p = __shfl_xor(res, 1);
        if (!(c & 1)) hb_out[node * 32 + (c >> 1)] = pack_bf16(res, p);
    }
}

// ---------------- read-out ----------------
// batch is sorted: a wave's 64 consecutive nodes almost always share one
// graph -> column-sum fast path (1 reduce + 1 atomic per wave).
__global__ void readout_fused(const float* __restrict__ h,
                              const float* __restrict__ W_out,
                              const float* __restrict__ b_out,
                              const int* __restrict__ batch,
                              float* __restrict__ sums,
                              float* __restrict__ counts) {
    __shared__ float s_sum[NG];
    __shared__ float s_cnt[NG];
    int tid = threadIdx.x;
    if (tid < NG) { s_sum[tid] = 0.f; s_cnt[tid] = 0.f; }
    __syncthreads();

    int lane = tid & 63;
    int wave = tid >> 6;
    int base = blockIdx.x * 256 + wave * 64;
    float w = W_out[lane];
    float b0 = b_out[0];

    if (base < NN) {
        int last = base + 63;
        bool full = (last < NN);
        int gf = batch[base];
        int gl = batch[full ? last : (NN - 1)];
        if (full && gf == gl) {
            // fast path: all 64 nodes in one graph
            float p = 0.f;
            for (int i = 0; i < 64; i++) p += h[(base + i) * C + lane];
            p *= w;
#pragma unroll
            for (int off = 32; off; off >>= 1) p += __shfl_xor(p, off);
            if (lane == 0) {
                atomicAdd(&s_sum[gf], p + 64.f * b0);
                atomicAdd(&s_cnt[gf], 64.f);
            }
        } else {
            float y_local = 0.f;
            for (int i = 0; i < 64; i++) {
                int nd = base + i;
                float v = 0.f;
                if (nd < NN) v = h[nd * C + lane] * w;
#pragma unroll
                for (int off = 32; off; off >>= 1) v += __shfl_xor(v, off);
                if (lane == i) y_local = v + b0;
            }
            int nd = base + lane;
            if (nd < NN) {
                int g = batch[nd];
                atomicAdd(&s_sum[g], y_local);
                atomicAdd(&s_cnt[g], 1.0f);
            }
        }
    }
    __syncthreads();
    if (tid < NG && s_cnt[tid] != 0.f) {
        atomicAdd(&sums[tid], s_sum[tid]);
        atomicAdd(&counts[tid], s_cnt[tid]);
    }
}

__global__ void finalize_kernel(const float* __restrict__ sums,
                                const float* __restrict__ counts,
                                float* __restrict__ out) {
    int g = threadIdx.x;
    if (g < NG) out[g] = sums[g] / fmaxf(counts[g], 1.0f);
}

extern "C" void kernel_launch(void* const* d_in, const int* in_sizes, int n_in,
                              void* d_out, int out_size, void* d_ws, size_t ws_size,
                              hipStream_t stream) {
    const float* state     = (const float*)d_in[0];
    const float* action    = (const float*)d_in[1];
    const int*   edge_index= (const int*)d_in[2];
    const float* edge_attr = (const float*)d_in[3];
    const int*   batch     = (const int*)d_in[4];
    const float* W_in      = (const float*)d_in[5];
    const float* b_in      = (const float*)d_in[6];
    const float* W_self    = (const float*)d_in[7];
    const float* W_nbr     = (const float*)d_in[8];
    const float* W_edge    = (const float*)d_in[9];
    const float* b_conv    = (const float*)d_in[10];
    const float* W_out     = (const float*)d_in[11];
    const float* b_out     = (const float*)d_in[12];
    float* out = (float*)d_out;

    const int* src = edge_index;        // edge_index[0,:]
    const int* dst = edge_index + NE;   // edge_index[1,:]

    // workspace layout (4-byte elements)
    float* ws      = (float*)d_ws;
    float* h0      = ws;                      // NN*C
    float* h1      = h0 + NN * C;             // NN*C
    float* agg_e   = h1 + NN * C;             // NN*IN_DIM
    float* sums    = agg_e + NN * IN_DIM;     // NG
    float* counts  = sums + NG;               // NG
    int*   deg     = (int*)(counts + NG);     // NN
    int*   excl    = deg + NN;                // NN
    int*   row_start = excl + NN;             // NN
    int*   cursor  = row_start + NN;          // NN
    int*   bsum    = cursor + NN;             // 256
    int*   bexcl   = bsum + 256;              // 256 (unused now)
    int*   csr_src = bexcl + 256;             // NE
    int*   csr_eid = csr_src + NE;            // NE
    uint32_t* hb0  = (uint32_t*)(csr_eid + NE); // NN*32
    uint32_t* hb1  = hb0 + NN * 32;             // NN*32

    hipMemsetAsync(deg, 0, NN * sizeof(int), stream);
    hipMemsetAsync(sums, 0, 2 * NG * sizeof(float), stream);

    const int THREADS = 256;
    int node_blocks = (NN + 3) / 4;
    int edge_tblocks = (NE + THREADS - 1) / THREADS;

    readin_kernel<<<node_blocks, THREADS, 0, stream>>>(state, action, W_in, b_in, h0, hb0);

    hist_kernel<<<edge_tblocks, THREADS, 0, stream>>>(dst, deg);
    scan1_kernel<<<SCAN_BLOCKS, 256, 0, stream>>>(deg, excl, bsum);
    scan23_kernel<<<SCAN_BLOCKS, 256, 0, stream>>>(excl, bsum, row_start, cursor);
    fill_kernel<<<edge_tblocks, THREADS, 0, stream>>>(src, dst, cursor, csr_src, csr_eid);

    agg_e_gather<<<node_blocks, THREADS, 0, stream>>>(edge_attr, row_start, deg, csr_eid, agg_e);

    int layer_blocks = (NN + 7) / 8;
    layer_kernel<<<layer_blocks, 512, 0, stream>>>(
        h0, hb0, row_start, deg, csr_src, agg_e,
        W_self, W_nbr, W_edge, b_conv, h1, hb1, 1);
    layer_kernel<<<layer_blocks, 512, 0, stream>>>(
        h1, hb1, row_start, deg, csr_src, agg_e,
        W_self + C * C, W_nbr + C * C, W_edge + IN_DIM * C, b_conv + C, h0, hb0, 0);

    int ro_blocks = (NN + 255) / 256;
    readout_fused<<<ro_blocks, THREADS, 0, stream>>>(h0, W_out, b_out, batch, sums, counts);
    finalize_kernel<<<1, 128, 0, stream>>>(sums, counts, out);
}

// Round 7
// 348.489 us; speedup vs baseline: 3.2182x; 1.4212x over previous
//
#include <hip/hip_runtime.h>

#define NN 50000
#define NE 800000
#define NG 128
#define IN_DIM 12
#define C 64
#define NEG_SLOPE 0.01f
#define SCAN_BLOCKS 196   // ceil(NN/256)

typedef short short8 __attribute__((ext_vector_type(8)));
typedef float f32x4 __attribute__((ext_vector_type(4)));
typedef unsigned int uint4v __attribute__((ext_vector_type(4)));

__device__ __forceinline__ float lrelu(float v) {
    return v > 0.f ? v : NEG_SLOPE * v;
}
__device__ __forceinline__ float bflo(uint32_t v) { return __uint_as_float(v << 16); }
__device__ __forceinline__ float bfhi(uint32_t v) { return __uint_as_float(v & 0xffff0000u); }
__device__ __forceinline__ unsigned short bf16r(float x) {   // RNE f32->bf16
    uint32_t u = __float_as_uint(x);
    u += 0x7fffu + ((u >> 16) & 1u);
    return (unsigned short)(u >> 16);
}
__device__ __forceinline__ uint32_t pack_bf16(float lo, float hi) {
    return (uint32_t)bf16r(lo) | ((uint32_t)bf16r(hi) << 16);
}

// ---------------- read-in: h (bf16 rows only) ----------------
__global__ void readin_kernel(const float* __restrict__ state,
                              const float* __restrict__ action,
                              const float* __restrict__ W_in,
                              const float* __restrict__ b_in,
                              uint32_t* __restrict__ hb) {
    __shared__ float sW[IN_DIM * C];
    __shared__ float sb[C];
    int tid = threadIdx.x;
    for (int i = tid; i < IN_DIM * C; i += blockDim.x) sW[i] = W_in[i];
    if (tid < C) sb[tid] = b_in[tid];
    __syncthreads();

    int node = blockIdx.x * (blockDim.x >> 6) + (tid >> 6);
    int c = tid & 63;
    if (node >= NN) return;

    float x[IN_DIM];
#pragma unroll
    for (int k = 0; k < 8; k++) x[k] = state[node * 8 + k];
#pragma unroll
    for (int k = 0; k < 4; k++) x[8 + k] = action[node * 4 + k];

    float acc = sb[c];
#pragma unroll
    for (int k = 0; k < IN_DIM; k++) acc += x[k] * sW[k * C + c];
    float res = lrelu(acc);
    float p = __shfl_xor(res, 1);
    if (!(c & 1)) hb[node * 32 + (c >> 1)] = pack_bf16(res, p);
}

// ---------------- CSR build ----------------
__global__ void hist_kernel(const int* __restrict__ dst, int* __restrict__ deg) {
    int e = blockIdx.x * blockDim.x + threadIdx.x;
    if (e < NE) atomicAdd(&deg[dst[e]], 1);
}

__global__ void scan1_kernel(const int* __restrict__ deg,
                             int* __restrict__ excl,
                             int* __restrict__ bsum) {
    __shared__ int tmp[256];
    int tid = threadIdx.x;
    int i = blockIdx.x * 256 + tid;
    int v = (i < NN) ? deg[i] : 0;
    tmp[tid] = v;
    __syncthreads();
    for (int off = 1; off < 256; off <<= 1) {
        int t = (tid >= off) ? tmp[tid - off] : 0;
        __syncthreads();
        tmp[tid] += t;
        __syncthreads();
    }
    if (i < NN) excl[i] = tmp[tid] - v;
    if (tid == 255) bsum[blockIdx.x] = tmp[255];
}

__global__ void scan23_kernel(const int* __restrict__ excl,
                              const int* __restrict__ bsum,
                              int* __restrict__ row_start,
                              int* __restrict__ cursor) {
    __shared__ int s_off;
    int tid = threadIdx.x;
    if (tid < 64) {
        int p = 0;
        for (int i = tid; i < blockIdx.x; i += 64) p += bsum[i];
#pragma unroll
        for (int off = 32; off; off >>= 1) p += __shfl_xor(p, off);
        if (tid == 0) s_off = p;
    }
    __syncthreads();
    int i = blockIdx.x * 256 + tid;
    if (i < NN) {
        int v = excl[i] + s_off;
        row_start[i] = v;
        cursor[i] = v;
    }
}

__global__ void fill_kernel(const int* __restrict__ src,
                            const int* __restrict__ dst,
                            int* __restrict__ cursor,
                            int* __restrict__ csr_src,
                            int* __restrict__ csr_eid) {
    int e = blockIdx.x * blockDim.x + threadIdx.x;
    if (e >= NE) return;
    int d = dst[e];
    int slot = atomicAdd(&cursor[d], 1);
    csr_src[slot] = src[e];
    csr_eid[slot] = e;
}

// ---------------- weight prep: WT[l][col][k] bf16, K = [W_self; W_nbr] ----------------
__global__ void wprep_kernel(const float* __restrict__ W_self,
                             const float* __restrict__ W_nbr,
                             unsigned short* __restrict__ WT) {
    int idx = blockIdx.x * 256 + threadIdx.x;   // 2*64*128 = 16384
    if (idx >= 2 * 64 * 128) return;
    int l = idx >> 13;
    int rem = idx & 8191;
    int col = rem >> 7;
    int k = rem & 127;
    float v = (k < C) ? W_self[l * C * C + k * C + col]
                      : W_nbr[l * C * C + (k - C) * C + col];
    WT[idx] = bf16r(v);
}

// ---------------- agg_e gather + E0/E1 edge-MLP (layer-invariant, f32) ----------------
__global__ void agg_e_kernel(const float* __restrict__ edge_attr,
                             const int* __restrict__ row_start,
                             const int* __restrict__ deg,
                             const int* __restrict__ csr_eid,
                             const float* __restrict__ W_edge,
                             const float* __restrict__ b_conv,
                             float* __restrict__ E0,
                             float* __restrict__ E1) {
    __shared__ float sWe0[IN_DIM * C];
    __shared__ float sWe1[IN_DIM * C];
    __shared__ float sb0[C];
    __shared__ float sb1[C];
    int tid = threadIdx.x;
    for (int i = tid; i < IN_DIM * C; i += blockDim.x) {
        sWe0[i] = W_edge[i];
        sWe1[i] = W_edge[IN_DIM * C + i];
    }
    if (tid < C) { sb0[tid] = b_conv[tid]; sb1[tid] = b_conv[C + tid]; }
    __syncthreads();

    int node = blockIdx.x * (blockDim.x >> 6) + (tid >> 6);
    int lane = tid & 63;
    int g = lane >> 4;
    int cc = lane & 15;
    if (node >= NN) return;
    int start = row_start[node], cnt = deg[node];

    int myeid = (lane < cnt) ? csr_eid[start + lane] : 0;
    int nb = cnt < 64 ? cnt : 64;

    float acc = 0.f, acc2 = 0.f;
    int j = 0;
    for (; j + 8 <= nb; j += 8) {
        int e0 = __shfl(myeid, j + g);
        int e1 = __shfl(myeid, j + 4 + g);
        if (cc < IN_DIM) {
            acc  += edge_attr[e0 * IN_DIM + cc];
            acc2 += edge_attr[e1 * IN_DIM + cc];
        }
    }
    for (; j + 4 <= nb; j += 4) {
        int e0 = __shfl(myeid, j + g);
        if (cc < IN_DIM) acc += edge_attr[e0 * IN_DIM + cc];
    }
    {
        int e0 = __shfl(myeid, (j + g < 64) ? (j + g) : 0);
        if (j + g < nb && cc < IN_DIM) acc += edge_attr[e0 * IN_DIM + cc];
    }
    for (int i2 = 64 + g; i2 < cnt; i2 += 4) {
        int e = csr_eid[start + i2];
        if (cc < IN_DIM) acc += edge_attr[e * IN_DIM + cc];
    }
    acc += acc2;
    acc += __shfl_xor(acc, 16);
    acc += __shfl_xor(acc, 32);
    // every lane now holds agg_e[node][lane&15]; broadcast k=0..11 and GEMV
    float e0v = sb0[lane];
    float e1v = sb1[lane];
#pragma unroll
    for (int k = 0; k < IN_DIM; k++) {
        float ak = __shfl(acc, k);
        e0v += ak * sWe0[k * C + lane];
        e1v += ak * sWe1[k * C + lane];
    }
    E0[node * C + lane] = e0v;
    E1[node * C + lane] = e1v;
}

// ---------------- neighbor gather: aggb[n] = sum_{e in} hb[src] (bf16 rows) ----------------
__global__ void gather_kernel(const uint32_t* __restrict__ hb_in,
                              const int* __restrict__ row_start,
                              const int* __restrict__ deg,
                              const int* __restrict__ csr_src,
                              uint32_t* __restrict__ aggb) {
    int tid = threadIdx.x;
    int node = blockIdx.x * (blockDim.x >> 6) + (tid >> 6);
    int lane = tid & 63;
    if (node >= NN) return;

    int start = row_start[node], cnt = deg[node];
    int half = lane >> 5;
    int q = lane & 31;

    int myidx = (lane < cnt) ? csr_src[start + lane] : 0;
    int nb = cnt < 64 ? cnt : 64;

    float a0 = 0.f, a1 = 0.f, b0v = 0.f, b1v = 0.f;
    int j = 0;
    for (; j + 8 <= nb; j += 8) {
        int p = j + 4 * half;
        int s0 = __shfl(myidx, p);
        int s1 = __shfl(myidx, p + 1);
        int s2 = __shfl(myidx, p + 2);
        int s3 = __shfl(myidx, p + 3);
        uint32_t v0 = hb_in[s0 * 32 + q];
        uint32_t v1 = hb_in[s1 * 32 + q];
        uint32_t v2 = hb_in[s2 * 32 + q];
        uint32_t v3 = hb_in[s3 * 32 + q];
        a0  += bflo(v0); a1  += bfhi(v0);
        b0v += bflo(v1); b1v += bfhi(v1);
        a0  += bflo(v2); a1  += bfhi(v2);
        b0v += bflo(v3); b1v += bfhi(v3);
    }
    for (; j + 2 <= nb; j += 2) {
        int s = __shfl(myidx, j + half);
        uint32_t v = hb_in[s * 32 + q];
        a0 += bflo(v); a1 += bfhi(v);
    }
    {
        int s = __shfl(myidx, (j < 64) ? j : 0);
        if (j < nb && half == 0) {
            uint32_t v = hb_in[s * 32 + q];
            a0 += bflo(v); a1 += bfhi(v);
        }
    }
    for (int i2 = 64 + half; i2 < cnt; i2 += 2) {
        int s = csr_src[start + i2];
        uint32_t v = hb_in[s * 32 + q];
        a0 += bflo(v); a1 += bfhi(v);
    }
    a0 += b0v; a1 += b1v;
    a0 += __shfl_xor(a0, 32);
    a1 += __shfl_xor(a1, 32);
    if (lane < 32) aggb[node * 32 + q] = pack_bf16(a0, a1);
}

// ---------------- MFMA node update: hb_out = lrelu([hbA|aggb] @ Wcat + E) ----------------
// 16x16x32 bf16; per wave: one 16-node x 16-col tile, K=128 (4 MFMA).
// Block = 512 thr = 8 waves = 2 M-tiles x 4 N-tiles.
__global__ __launch_bounds__(512) void gemm_kernel(
        const uint32_t* __restrict__ hbA,      // [NN][32] bf16 pairs (K 0..63)
        const uint32_t* __restrict__ aggb,     // [NN][32] bf16 pairs (K 64..127)
        const unsigned short* __restrict__ WT, // [64][128] bf16 (layer slice)
        const float* __restrict__ E,           // [NN][64] f32 acc init
        unsigned short* __restrict__ hb_out) { // [NN][64] bf16
    int tid = threadIdx.x;
    int w = tid >> 6;
    int l = tid & 63;
    int mt = blockIdx.x * 2 + (w >> 2);
    if (mt * 16 >= NN) return;
    int nt = w & 3;
    int node_base = mt * 16;

    int arow = l & 15;            // A row within tile / B col within tile
    int kg = l >> 4;              // k-group of 8
    int gcol = nt * 16 + arow;    // global output column for B/C

    // A fragments: kk=0,1 from hbA, kk=2,3 from aggb
    const uint32_t* aptr = hbA + (node_base + arow) * 32 + kg * 4;
    const uint32_t* gptr = aggb + (node_base + arow) * 32 + kg * 4;
    short8 a0 = __builtin_bit_cast(short8, *reinterpret_cast<const uint4v*>(aptr));
    short8 a1 = __builtin_bit_cast(short8, *reinterpret_cast<const uint4v*>(aptr + 16));
    short8 a2 = __builtin_bit_cast(short8, *reinterpret_cast<const uint4v*>(gptr));
    short8 a3 = __builtin_bit_cast(short8, *reinterpret_cast<const uint4v*>(gptr + 16));

    // B fragments: WT[gcol][kk*32 + kg*8 .. +7]
    const unsigned short* bbase = WT + gcol * 128 + kg * 8;
    short8 b0 = __builtin_bit_cast(short8, *reinterpret_cast<const uint4v*>(bbase));
    short8 b1 = __builtin_bit_cast(short8, *reinterpret_cast<const uint4v*>(bbase + 32));
    short8 b2 = __builtin_bit_cast(short8, *reinterpret_cast<const uint4v*>(bbase + 64));
    short8 b3 = __builtin_bit_cast(short8, *reinterpret_cast<const uint4v*>(bbase + 96));

    // acc init from E: C/D layout col=l&15, row=(l>>4)*4+reg
    f32x4 acc;
#pragma unroll
    for (int r = 0; r < 4; r++)
        acc[r] = E[(node_base + kg * 4 + r) * C + gcol];

    acc = __builtin_amdgcn_mfma_f32_16x16x32_bf16(a0, b0, acc, 0, 0, 0);
    acc = __builtin_amdgcn_mfma_f32_16x16x32_bf16(a1, b1, acc, 0, 0, 0);
    acc = __builtin_amdgcn_mfma_f32_16x16x32_bf16(a2, b2, acc, 0, 0, 0);
    acc = __builtin_amdgcn_mfma_f32_16x16x32_bf16(a3, b3, acc, 0, 0, 0);

#pragma unroll
    for (int r = 0; r < 4; r++) {
        float res = lrelu(acc[r]);
        hb_out[(node_base + kg * 4 + r) * C + gcol] = bf16r(res);
    }
}

// ---------------- read-out (bf16 h) ----------------
__global__ void readout_fused(const unsigned short* __restrict__ hb,
                              const float* __restrict__ W_out,
                              const float* __restrict__ b_out,
                              const int* __restrict__ batch,
                              float* __restrict__ sums,
                              float* __restrict__ counts) {
    __shared__ float s_sum[NG];
    __shared__ float s_cnt[NG];
    int tid = threadIdx.x;
    if (tid < NG) { s_sum[tid] = 0.f; s_cnt[tid] = 0.f; }
    __syncthreads();

    int lane = tid & 63;
    int wave = tid >> 6;
    int base = blockIdx.x * 256 + wave * 64;
    float w = W_out[lane];
    float b0 = b_out[0];

    if (base < NN) {
        int last = base + 63;
        bool full = (last < NN);
        int gf = batch[base];
        int gl = batch[full ? last : (NN - 1)];
        if (full && gf == gl) {
            float p = 0.f;
            for (int i = 0; i < 64; i++)
                p += __uint_as_float((uint32_t)hb[(base + i) * C + lane] << 16);
            p *= w;
#pragma unroll
            for (int off = 32; off; off >>= 1) p += __shfl_xor(p, off);
            if (lane == 0) {
                atomicAdd(&s_sum[gf], p + 64.f * b0);
                atomicAdd(&s_cnt[gf], 64.f);
            }
        } else {
            float y_local = 0.f;
            for (int i = 0; i < 64; i++) {
                int nd = base + i;
                float v = 0.f;
                if (nd < NN) v = __uint_as_float((uint32_t)hb[nd * C + lane] << 16) * w;
#pragma unroll
                for (int off = 32; off; off >>= 1) v += __shfl_xor(v, off);
                if (lane == i) y_local = v + b0;
            }
            int nd = base + lane;
            if (nd < NN) {
                int g = batch[nd];
                atomicAdd(&s_sum[g], y_local);
                atomicAdd(&s_cnt[g], 1.0f);
            }
        }
    }
    __syncthreads();
    if (tid < NG && s_cnt[tid] != 0.f) {
        atomicAdd(&sums[tid], s_sum[tid]);
        atomicAdd(&counts[tid], s_cnt[tid]);
    }
}

__global__ void finalize_kernel(const float* __restrict__ sums,
                                const float* __restrict__ counts,
                                float* __restrict__ out) {
    int g = threadIdx.x;
    if (g < NG) out[g] = sums[g] / fmaxf(counts[g], 1.0f);
}

extern "C" void kernel_launch(void* const* d_in, const int* in_sizes, int n_in,
                              void* d_out, int out_size, void* d_ws, size_t ws_size,
                              hipStream_t stream) {
    const float* state     = (const float*)d_in[0];
    const float* action    = (const float*)d_in[1];
    const int*   edge_index= (const int*)d_in[2];
    const float* edge_attr = (const float*)d_in[3];
    const int*   batch     = (const int*)d_in[4];
    const float* W_in      = (const float*)d_in[5];
    const float* b_in      = (const float*)d_in[6];
    const float* W_self    = (const float*)d_in[7];
    const float* W_nbr     = (const float*)d_in[8];
    const float* W_edge    = (const float*)d_in[9];
    const float* b_conv    = (const float*)d_in[10];
    const float* W_out     = (const float*)d_in[11];
    const float* b_out     = (const float*)d_in[12];
    float* out = (float*)d_out;

    const int* src = edge_index;
    const int* dst = edge_index + NE;

    // workspace layout (4-byte units)
    float* ws      = (float*)d_ws;
    float* E0      = ws;                      // NN*C f32
    float* E1      = E0 + NN * C;             // NN*C f32
    float* sums    = E1 + NN * C;             // NG
    float* counts  = sums + NG;               // NG
    int*   deg     = (int*)(counts + NG);     // NN
    int*   excl    = deg + NN;                // NN
    int*   row_start = excl + NN;             // NN
    int*   cursor  = row_start + NN;          // NN
    int*   bsum    = cursor + NN;             // 256
    int*   csr_src = bsum + 256;              // NE
    int*   csr_eid = csr_src + NE;            // NE
    uint32_t* hb_a = (uint32_t*)(csr_eid + NE);  // NN*32
    uint32_t* hb_b = hb_a + NN * 32;             // NN*32
    uint32_t* aggb = hb_b + NN * 32;             // NN*32
    unsigned short* WT = (unsigned short*)(aggb + NN * 32);  // 2*64*128 bf16

    hipMemsetAsync(deg, 0, NN * sizeof(int), stream);
    hipMemsetAsync(sums, 0, 2 * NG * sizeof(float), stream);

    const int THREADS = 256;
    int node_blocks = (NN + 3) / 4;
    int edge_tblocks = (NE + THREADS - 1) / THREADS;

    readin_kernel<<<node_blocks, THREADS, 0, stream>>>(state, action, W_in, b_in, hb_a);

    hist_kernel<<<edge_tblocks, THREADS, 0, stream>>>(dst, deg);
    scan1_kernel<<<SCAN_BLOCKS, 256, 0, stream>>>(deg, excl, bsum);
    scan23_kernel<<<SCAN_BLOCKS, 256, 0, stream>>>(excl, bsum, row_start, cursor);
    fill_kernel<<<edge_tblocks, THREADS, 0, stream>>>(src, dst, cursor, csr_src, csr_eid);

    wprep_kernel<<<64, 256, 0, stream>>>(W_self, W_nbr, WT);

    agg_e_kernel<<<node_blocks, THREADS, 0, stream>>>(
        edge_attr, row_start, deg, csr_eid, W_edge, b_conv, E0, E1);

    int gemm_blocks = (3125 + 1) / 2;   // 3125 M-tiles of 16 nodes, 2 per block

    // layer 0: hb_a -> hb_b
    gather_kernel<<<node_blocks, THREADS, 0, stream>>>(hb_a, row_start, deg, csr_src, aggb);
    gemm_kernel<<<gemm_blocks, 512, 0, stream>>>(
        hb_a, aggb, WT, E0, (unsigned short*)hb_b);

    // layer 1: hb_b -> hb_a
    gather_kernel<<<node_blocks, THREADS, 0, stream>>>(hb_b, row_start, deg, csr_src, aggb);
    gemm_kernel<<<gemm_blocks, 512, 0, stream>>>(
        hb_b, aggb, WT + 64 * 128, E1, (unsigned short*)hb_a);

    int ro_blocks = (NN + 255) / 256;
    readout_fused<<<ro_blocks, THREADS, 0, stream>>>(
        (const unsigned short*)hb_a, W_out, b_out, batch, sums, counts);
    finalize_kernel<<<1, 128, 0, stream>>>(sums, counts, out);
}

// Round 8
// 338.234 us; speedup vs baseline: 3.3157x; 1.0303x over previous
//
#include <hip/hip_runtime.h>

#define NN 50000
#define NE 800000
#define NG 128
#define IN_DIM 12
#define C 64
#define NEG_SLOPE 0.01f
#define SCAN_BLOCKS 196   // ceil(NN/256)
#define NOWN 8            // XCD count: owner-partitioned scatter
#define OWN_RANGE 6250    // NN / NOWN (exact)
#define ESTRIPE 2048
#define NSTRIPES ((NE + ESTRIPE - 1) / ESTRIPE)   // 391

typedef short short8 __attribute__((ext_vector_type(8)));
typedef float f32x4 __attribute__((ext_vector_type(4)));
typedef unsigned int uint4v __attribute__((ext_vector_type(4)));

__device__ __forceinline__ float lrelu(float v) {
    return v > 0.f ? v : NEG_SLOPE * v;
}
__device__ __forceinline__ float bflo(uint32_t v) { return __uint_as_float(v << 16); }
__device__ __forceinline__ float bfhi(uint32_t v) { return __uint_as_float(v & 0xffff0000u); }
__device__ __forceinline__ unsigned short bf16r(float x) {   // RNE f32->bf16
    uint32_t u = __float_as_uint(x);
    u += 0x7fffu + ((u >> 16) & 1u);
    return (unsigned short)(u >> 16);
}
__device__ __forceinline__ uint32_t pack_bf16(float lo, float hi) {
    return (uint32_t)bf16r(lo) | ((uint32_t)bf16r(hi) << 16);
}

// ---------------- read-in: h (bf16 rows only) ----------------
__global__ void readin_kernel(const float* __restrict__ state,
                              const float* __restrict__ action,
                              const float* __restrict__ W_in,
                              const float* __restrict__ b_in,
                              uint32_t* __restrict__ hb) {
    __shared__ float sW[IN_DIM * C];
    __shared__ float sb[C];
    int tid = threadIdx.x;
    for (int i = tid; i < IN_DIM * C; i += blockDim.x) sW[i] = W_in[i];
    if (tid < C) sb[tid] = b_in[tid];
    __syncthreads();

    int node = blockIdx.x * (blockDim.x >> 6) + (tid >> 6);
    int c = tid & 63;
    if (node >= NN) return;

    float x[IN_DIM];
#pragma unroll
    for (int k = 0; k < 8; k++) x[k] = state[node * 8 + k];
#pragma unroll
    for (int k = 0; k < 4; k++) x[8 + k] = action[node * 4 + k];

    float acc = sb[c];
#pragma unroll
    for (int k = 0; k < IN_DIM; k++) acc += x[k] * sW[k * C + c];
    float res = lrelu(acc);
    float p = __shfl_xor(res, 1);
    if (!(c & 1)) hb[node * 32 + (c >> 1)] = pack_bf16(res, p);
}

// ---------------- CSR build (owner-partitioned: block b owns dst range (b&7)) ----------------
__global__ void hist_part(const int* __restrict__ dst, int* __restrict__ deg) {
    int owner = blockIdx.x & (NOWN - 1);
    int stripe = blockIdx.x >> 3;
    int lo = owner * OWN_RANGE, hi = lo + OWN_RANGE;
    int base = stripe * ESTRIPE;
    int end = base + ESTRIPE; if (end > NE) end = NE;
    for (int e = base + threadIdx.x; e < end; e += 256) {
        int d = dst[e];
        if (d >= lo && d < hi) atomicAdd(&deg[d], 1);
    }
}

__global__ void scan1_kernel(const int* __restrict__ deg,
                             int* __restrict__ excl,
                             int* __restrict__ bsum) {
    __shared__ int tmp[256];
    int tid = threadIdx.x;
    int i = blockIdx.x * 256 + tid;
    int v = (i < NN) ? deg[i] : 0;
    tmp[tid] = v;
    __syncthreads();
    for (int off = 1; off < 256; off <<= 1) {
        int t = (tid >= off) ? tmp[tid - off] : 0;
        __syncthreads();
        tmp[tid] += t;
        __syncthreads();
    }
    if (i < NN) excl[i] = tmp[tid] - v;
    if (tid == 255) bsum[blockIdx.x] = tmp[255];
}

__global__ void scan23_kernel(const int* __restrict__ excl,
                              const int* __restrict__ bsum,
                              int* __restrict__ row_start,
                              int* __restrict__ cursor) {
    __shared__ int s_off;
    int tid = threadIdx.x;
    if (tid < 64) {
        int p = 0;
        for (int i = tid; i < blockIdx.x; i += 64) p += bsum[i];
#pragma unroll
        for (int off = 32; off; off >>= 1) p += __shfl_xor(p, off);
        if (tid == 0) s_off = p;
    }
    __syncthreads();
    int i = blockIdx.x * 256 + tid;
    if (i < NN) {
        int v = excl[i] + s_off;
        row_start[i] = v;
        cursor[i] = v;
    }
}

// owner-partitioned fill; single 8B {src, eid} store per edge (XCD-local slots)
__global__ void fill_part(const int* __restrict__ src,
                          const int* __restrict__ dst,
                          int* __restrict__ cursor,
                          int2* __restrict__ csr2) {
    int owner = blockIdx.x & (NOWN - 1);
    int stripe = blockIdx.x >> 3;
    int lo = owner * OWN_RANGE, hi = lo + OWN_RANGE;
    int base = stripe * ESTRIPE;
    int end = base + ESTRIPE; if (end > NE) end = NE;
    for (int e = base + threadIdx.x; e < end; e += 256) {
        int d = dst[e];
        if (d >= lo && d < hi) {
            int slot = atomicAdd(&cursor[d], 1);
            csr2[slot] = make_int2(src[e], e);
        }
    }
}

// ---------------- weight prep: WT[l][col][k] bf16, K = [W_self; W_nbr] ----------------
__global__ void wprep_kernel(const float* __restrict__ W_self,
                             const float* __restrict__ W_nbr,
                             unsigned short* __restrict__ WT) {
    int idx = blockIdx.x * 256 + threadIdx.x;   // 2*64*128 = 16384
    if (idx >= 2 * 64 * 128) return;
    int l = idx >> 13;
    int rem = idx & 8191;
    int col = rem >> 7;
    int k = rem & 127;
    float v = (k < C) ? W_self[l * C * C + k * C + col]
                      : W_nbr[l * C * C + (k - C) * C + col];
    WT[idx] = bf16r(v);
}

// ---------------- agg_e gather + E0/E1 edge-MLP (layer-invariant, f32) ----------------
__global__ void agg_e_kernel(const float* __restrict__ edge_attr,
                             const int* __restrict__ row_start,
                             const int* __restrict__ deg,
                             const int2* __restrict__ csr2,
                             const float* __restrict__ W_edge,
                             const float* __restrict__ b_conv,
                             float* __restrict__ E0,
                             float* __restrict__ E1) {
    __shared__ float sWe0[IN_DIM * C];
    __shared__ float sWe1[IN_DIM * C];
    __shared__ float sb0[C];
    __shared__ float sb1[C];
    int tid = threadIdx.x;
    for (int i = tid; i < IN_DIM * C; i += blockDim.x) {
        sWe0[i] = W_edge[i];
        sWe1[i] = W_edge[IN_DIM * C + i];
    }
    if (tid < C) { sb0[tid] = b_conv[tid]; sb1[tid] = b_conv[C + tid]; }
    __syncthreads();

    int node = blockIdx.x * (blockDim.x >> 6) + (tid >> 6);
    int lane = tid & 63;
    int g = lane >> 4;
    int cc = lane & 15;
    if (node >= NN) return;
    int start = row_start[node], cnt = deg[node];

    int myeid = (lane < cnt) ? csr2[start + lane].y : 0;
    int nb = cnt < 64 ? cnt : 64;

    float acc = 0.f, acc2 = 0.f;
    int j = 0;
    for (; j + 8 <= nb; j += 8) {
        int e0 = __shfl(myeid, j + g);
        int e1 = __shfl(myeid, j + 4 + g);
        if (cc < IN_DIM) {
            acc  += edge_attr[e0 * IN_DIM + cc];
            acc2 += edge_attr[e1 * IN_DIM + cc];
        }
    }
    for (; j + 4 <= nb; j += 4) {
        int e0 = __shfl(myeid, j + g);
        if (cc < IN_DIM) acc += edge_attr[e0 * IN_DIM + cc];
    }
    {
        int e0 = __shfl(myeid, (j + g < 64) ? (j + g) : 0);
        if (j + g < nb && cc < IN_DIM) acc += edge_attr[e0 * IN_DIM + cc];
    }
    for (int i2 = 64 + g; i2 < cnt; i2 += 4) {
        int e = csr2[start + i2].y;
        if (cc < IN_DIM) acc += edge_attr[e * IN_DIM + cc];
    }
    acc += acc2;
    acc += __shfl_xor(acc, 16);
    acc += __shfl_xor(acc, 32);
    // every lane now holds agg_e[node][lane&15]; broadcast k=0..11 and GEMV
    float e0v = sb0[lane];
    float e1v = sb1[lane];
#pragma unroll
    for (int k = 0; k < IN_DIM; k++) {
        float ak = __shfl(acc, k);
        e0v += ak * sWe0[k * C + lane];
        e1v += ak * sWe1[k * C + lane];
    }
    E0[node * C + lane] = e0v;
    E1[node * C + lane] = e1v;
}

// ---------------- neighbor gather: aggb[n] = sum_{e in} hb[src] (bf16 rows) ----------------
__global__ void gather_kernel(const uint32_t* __restrict__ hb_in,
                              const int* __restrict__ row_start,
                              const int* __restrict__ deg,
                              const int2* __restrict__ csr2,
                              uint32_t* __restrict__ aggb) {
    int tid = threadIdx.x;
    int node = blockIdx.x * (blockDim.x >> 6) + (tid >> 6);
    int lane = tid & 63;
    if (node >= NN) return;

    int start = row_start[node], cnt = deg[node];
    int half = lane >> 5;
    int q = lane & 31;

    int myidx = (lane < cnt) ? csr2[start + lane].x : 0;
    int nb = cnt < 64 ? cnt : 64;

    float a0 = 0.f, a1 = 0.f, b0v = 0.f, b1v = 0.f;
    float c0 = 0.f, c1 = 0.f, d0 = 0.f, d1 = 0.f;
    int j = 0;
    for (; j + 16 <= nb; j += 16) {     // 8 independent loads in flight per half
        int p = j + 4 * half;
        int s0 = __shfl(myidx, p);
        int s1 = __shfl(myidx, p + 1);
        int s2 = __shfl(myidx, p + 2);
        int s3 = __shfl(myidx, p + 3);
        int s4 = __shfl(myidx, p + 8);
        int s5 = __shfl(myidx, p + 9);
        int s6 = __shfl(myidx, p + 10);
        int s7 = __shfl(myidx, p + 11);
        uint32_t v0 = hb_in[s0 * 32 + q];
        uint32_t v1 = hb_in[s1 * 32 + q];
        uint32_t v2 = hb_in[s2 * 32 + q];
        uint32_t v3 = hb_in[s3 * 32 + q];
        uint32_t v4 = hb_in[s4 * 32 + q];
        uint32_t v5 = hb_in[s5 * 32 + q];
        uint32_t v6 = hb_in[s6 * 32 + q];
        uint32_t v7 = hb_in[s7 * 32 + q];
        a0  += bflo(v0); a1  += bfhi(v0);
        b0v += bflo(v1); b1v += bfhi(v1);
        c0  += bflo(v2); c1  += bfhi(v2);
        d0  += bflo(v3); d1  += bfhi(v3);
        a0  += bflo(v4); a1  += bfhi(v4);
        b0v += bflo(v5); b1v += bfhi(v5);
        c0  += bflo(v6); c1  += bfhi(v6);
        d0  += bflo(v7); d1  += bfhi(v7);
    }
    for (; j + 8 <= nb; j += 8) {
        int p = j + 4 * half;
        int s0 = __shfl(myidx, p);
        int s1 = __shfl(myidx, p + 1);
        int s2 = __shfl(myidx, p + 2);
        int s3 = __shfl(myidx, p + 3);
        uint32_t v0 = hb_in[s0 * 32 + q];
        uint32_t v1 = hb_in[s1 * 32 + q];
        uint32_t v2 = hb_in[s2 * 32 + q];
        uint32_t v3 = hb_in[s3 * 32 + q];
        a0  += bflo(v0); a1  += bfhi(v0);
        b0v += bflo(v1); b1v += bfhi(v1);
        c0  += bflo(v2); c1  += bfhi(v2);
        d0  += bflo(v3); d1  += bfhi(v3);
    }
    for (; j + 2 <= nb; j += 2) {
        int s = __shfl(myidx, j + half);
        uint32_t v = hb_in[s * 32 + q];
        a0 += bflo(v); a1 += bfhi(v);
    }
    {
        int s = __shfl(myidx, (j < 64) ? j : 0);
        if (j < nb && half == 0) {
            uint32_t v = hb_in[s * 32 + q];
            a0 += bflo(v); a1 += bfhi(v);
        }
    }
    for (int i2 = 64 + half; i2 < cnt; i2 += 2) {
        int s = csr2[start + i2].x;
        uint32_t v = hb_in[s * 32 + q];
        a0 += bflo(v); a1 += bfhi(v);
    }
    a0 += b0v + c0 + d0;
    a1 += b1v + c1 + d1;
    a0 += __shfl_xor(a0, 32);
    a1 += __shfl_xor(a1, 32);
    if (lane < 32) aggb[node * 32 + q] = pack_bf16(a0, a1);
}

// ---------------- MFMA node update: hb_out = lrelu([hbA|aggb] @ Wcat + E) ----------------
__global__ __launch_bounds__(512) void gemm_kernel(
        const uint32_t* __restrict__ hbA,      // [NN][32] bf16 pairs (K 0..63)
        const uint32_t* __restrict__ aggb,     // [NN][32] bf16 pairs (K 64..127)
        const unsigned short* __restrict__ WT, // [64][128] bf16 (layer slice)
        const float* __restrict__ E,           // [NN][64] f32 acc init
        unsigned short* __restrict__ hb_out) { // [NN][64] bf16
    int tid = threadIdx.x;
    int w = tid >> 6;
    int l = tid & 63;
    int mt = blockIdx.x * 2 + (w >> 2);
    if (mt * 16 >= NN) return;
    int nt = w & 3;
    int node_base = mt * 16;

    int arow = l & 15;            // A row within tile / B col within tile
    int kg = l >> 4;              // k-group of 8
    int gcol = nt * 16 + arow;    // global output column for B/C

    const uint32_t* aptr = hbA + (node_base + arow) * 32 + kg * 4;
    const uint32_t* gptr = aggb + (node_base + arow) * 32 + kg * 4;
    short8 a0 = __builtin_bit_cast(short8, *reinterpret_cast<const uint4v*>(aptr));
    short8 a1 = __builtin_bit_cast(short8, *reinterpret_cast<const uint4v*>(aptr + 16));
    short8 a2 = __builtin_bit_cast(short8, *reinterpret_cast<const uint4v*>(gptr));
    short8 a3 = __builtin_bit_cast(short8, *reinterpret_cast<const uint4v*>(gptr + 16));

    const unsigned short* bbase = WT + gcol * 128 + kg * 8;
    short8 b0 = __builtin_bit_cast(short8, *reinterpret_cast<const uint4v*>(bbase));
    short8 b1 = __builtin_bit_cast(short8, *reinterpret_cast<const uint4v*>(bbase + 32));
    short8 b2 = __builtin_bit_cast(short8, *reinterpret_cast<const uint4v*>(bbase + 64));
    short8 b3 = __builtin_bit_cast(short8, *reinterpret_cast<const uint4v*>(bbase + 96));

    f32x4 acc;
#pragma unroll
    for (int r = 0; r < 4; r++)
        acc[r] = E[(node_base + kg * 4 + r) * C + gcol];

    acc = __builtin_amdgcn_mfma_f32_16x16x32_bf16(a0, b0, acc, 0, 0, 0);
    acc = __builtin_amdgcn_mfma_f32_16x16x32_bf16(a1, b1, acc, 0, 0, 0);
    acc = __builtin_amdgcn_mfma_f32_16x16x32_bf16(a2, b2, acc, 0, 0, 0);
    acc = __builtin_amdgcn_mfma_f32_16x16x32_bf16(a3, b3, acc, 0, 0, 0);

#pragma unroll
    for (int r = 0; r < 4; r++) {
        float res = lrelu(acc[r]);
        hb_out[(node_base + kg * 4 + r) * C + gcol] = bf16r(res);
    }
}

// ---------------- read-out (bf16 h) ----------------
__global__ void readout_fused(const unsigned short* __restrict__ hb,
                              const float* __restrict__ W_out,
                              const float* __restrict__ b_out,
                              const int* __restrict__ batch,
                              float* __restrict__ sums,
                              float* __restrict__ counts) {
    __shared__ float s_sum[NG];
    __shared__ float s_cnt[NG];
    int tid = threadIdx.x;
    if (tid < NG) { s_sum[tid] = 0.f; s_cnt[tid] = 0.f; }
    __syncthreads();

    int lane = tid & 63;
    int wave = tid >> 6;
    int base = blockIdx.x * 256 + wave * 64;
    float w = W_out[lane];
    float b0 = b_out[0];

    if (base < NN) {
        int last = base + 63;
        bool full = (last < NN);
        int gf = batch[base];
        int gl = batch[full ? last : (NN - 1)];
        if (full && gf == gl) {
            float p = 0.f;
            for (int i = 0; i < 64; i++)
                p += __uint_as_float((uint32_t)hb[(base + i) * C + lane] << 16);
            p *= w;
#pragma unroll
            for (int off = 32; off; off >>= 1) p += __shfl_xor(p, off);
            if (lane == 0) {
                atomicAdd(&s_sum[gf], p + 64.f * b0);
                atomicAdd(&s_cnt[gf], 64.f);
            }
        } else {
            float y_local = 0.f;
            for (int i = 0; i < 64; i++) {
                int nd = base + i;
                float v = 0.f;
                if (nd < NN) v = __uint_as_float((uint32_t)hb[nd * C + lane] << 16) * w;
#pragma unroll
                for (int off = 32; off; off >>= 1) v += __shfl_xor(v, off);
                if (lane == i) y_local = v + b0;
            }
            int nd = base + lane;
            if (nd < NN) {
                int g = batch[nd];
                atomicAdd(&s_sum[g], y_local);
                atomicAdd(&s_cnt[g], 1.0f);
            }
        }
    }
    __syncthreads();
    if (tid < NG && s_cnt[tid] != 0.f) {
        atomicAdd(&sums[tid], s_sum[tid]);
        atomicAdd(&counts[tid], s_cnt[tid]);
    }
}

__global__ void finalize_kernel(const float* __restrict__ sums,
                                const float* __restrict__ counts,
                                float* __restrict__ out) {
    int g = threadIdx.x;
    if (g < NG) out[g] = sums[g] / fmaxf(counts[g], 1.0f);
}

extern "C" void kernel_launch(void* const* d_in, const int* in_sizes, int n_in,
                              void* d_out, int out_size, void* d_ws, size_t ws_size,
                              hipStream_t stream) {
    const float* state     = (const float*)d_in[0];
    const float* action    = (const float*)d_in[1];
    const int*   edge_index= (const int*)d_in[2];
    const float* edge_attr = (const float*)d_in[3];
    const int*   batch     = (const int*)d_in[4];
    const float* W_in      = (const float*)d_in[5];
    const float* b_in      = (const float*)d_in[6];
    const float* W_self    = (const float*)d_in[7];
    const float* W_nbr     = (const float*)d_in[8];
    const float* W_edge    = (const float*)d_in[9];
    const float* b_conv    = (const float*)d_in[10];
    const float* W_out     = (const float*)d_in[11];
    const float* b_out     = (const float*)d_in[12];
    float* out = (float*)d_out;

    const int* src = edge_index;
    const int* dst = edge_index + NE;

    // workspace layout (4-byte units)
    float* ws      = (float*)d_ws;
    float* E0      = ws;                      // NN*C f32
    float* E1      = E0 + NN * C;             // NN*C f32
    float* sums    = E1 + NN * C;             // NG
    float* counts  = sums + NG;               // NG
    int*   deg     = (int*)(counts + NG);     // NN
    int*   excl    = deg + NN;                // NN
    int*   row_start = excl + NN;             // NN
    int*   cursor  = row_start + NN;          // NN
    int*   bsum    = cursor + NN;             // 256
    int2*  csr2    = (int2*)(bsum + 256);     // NE int2 (8B-aligned: offset even)
    uint32_t* hb_a = (uint32_t*)(csr2 + NE);  // NN*32
    uint32_t* hb_b = hb_a + NN * 32;          // NN*32
    uint32_t* aggb = hb_b + NN * 32;          // NN*32
    unsigned short* WT = (unsigned short*)(aggb + NN * 32);  // 2*64*128 bf16

    hipMemsetAsync(deg, 0, NN * sizeof(int), stream);
    hipMemsetAsync(sums, 0, 2 * NG * sizeof(float), stream);

    const int THREADS = 256;
    int node_blocks = (NN + 3) / 4;
    int part_blocks = NSTRIPES * NOWN;   // owner-partitioned edge kernels

    readin_kernel<<<node_blocks, THREADS, 0, stream>>>(state, action, W_in, b_in, hb_a);

    hist_part<<<part_blocks, THREADS, 0, stream>>>(dst, deg);
    scan1_kernel<<<SCAN_BLOCKS, 256, 0, stream>>>(deg, excl, bsum);
    scan23_kernel<<<SCAN_BLOCKS, 256, 0, stream>>>(excl, bsum, row_start, cursor);
    fill_part<<<part_blocks, THREADS, 0, stream>>>(src, dst, cursor, csr2);

    wprep_kernel<<<64, 256, 0, stream>>>(W_self, W_nbr, WT);

    agg_e_kernel<<<node_blocks, THREADS, 0, stream>>>(
        edge_attr, row_start, deg, csr2, W_edge, b_conv, E0, E1);

    int gemm_blocks = (3125 + 1) / 2;   // 3125 M-tiles of 16 nodes, 2 per block

    // layer 0: hb_a -> hb_b
    gather_kernel<<<node_blocks, THREADS, 0, stream>>>(hb_a, row_start, deg, csr2, aggb);
    gemm_kernel<<<gemm_blocks, 512, 0, stream>>>(
        hb_a, aggb, WT, E0, (unsigned short*)hb_b);

    // layer 1: hb_b -> hb_a
    gather_kernel<<<node_blocks, THREADS, 0, stream>>>(hb_b, row_start, deg, csr2, aggb);
    gemm_kernel<<<gemm_blocks, 512, 0, stream>>>(
        hb_b, aggb, WT + 64 * 128, E1, (unsigned short*)hb_a);

    int ro_blocks = (NN + 255) / 256;
    readout_fused<<<ro_blocks, THREADS, 0, stream>>>(
        (const unsigned short*)hb_a, W_out, b_out, batch, sums, counts);
    finalize_kernel<<<1, 128, 0, stream>>>(sums, counts, out);
}

// Round 9
// 335.640 us; speedup vs baseline: 3.3414x; 1.0077x over previous
//
#include <hip/hip_runtime.h>

#define NN 50000
#define NE 800000
#define NG 128
#define IN_DIM 12
#define C 64
#define KTOT 160          // [h(64) | agg_h(64) | agg_e(12) + pad(20)]
#define NEG_SLOPE 0.01f
#define SCAN_BLOCKS 196   // ceil(NN/256)
#define NOWN 8            // XCD count: owner-partitioned scatter
#define OWN_RANGE 6250    // NN / NOWN (exact)
#define ESTRIPE 2048
#define NSTRIPES ((NE + ESTRIPE - 1) / ESTRIPE)   // 391

typedef short short8 __attribute__((ext_vector_type(8)));
typedef float f32x4 __attribute__((ext_vector_type(4)));
typedef unsigned int uint4v __attribute__((ext_vector_type(4)));

__device__ __forceinline__ float lrelu(float v) {
    return v > 0.f ? v : NEG_SLOPE * v;
}
__device__ __forceinline__ float bflo(uint32_t v) { return __uint_as_float(v << 16); }
__device__ __forceinline__ float bfhi(uint32_t v) { return __uint_as_float(v & 0xffff0000u); }
__device__ __forceinline__ unsigned short bf16r(float x) {   // RNE f32->bf16
    uint32_t u = __float_as_uint(x);
    u += 0x7fffu + ((u >> 16) & 1u);
    return (unsigned short)(u >> 16);
}
__device__ __forceinline__ uint32_t pack_bf16(float lo, float hi) {
    return (uint32_t)bf16r(lo) | ((uint32_t)bf16r(hi) << 16);
}

// ---------------- read-in: h (bf16 rows only) ----------------
__global__ void readin_kernel(const float* __restrict__ state,
                              const float* __restrict__ action,
                              const float* __restrict__ W_in,
                              const float* __restrict__ b_in,
                              uint32_t* __restrict__ hb) {
    __shared__ float sW[IN_DIM * C];
    __shared__ float sb[C];
    int tid = threadIdx.x;
    for (int i = tid; i < IN_DIM * C; i += blockDim.x) sW[i] = W_in[i];
    if (tid < C) sb[tid] = b_in[tid];
    __syncthreads();

    int node = blockIdx.x * (blockDim.x >> 6) + (tid >> 6);
    int c = tid & 63;
    if (node >= NN) return;

    float x[IN_DIM];
#pragma unroll
    for (int k = 0; k < 8; k++) x[k] = state[node * 8 + k];
#pragma unroll
    for (int k = 0; k < 4; k++) x[8 + k] = action[node * 4 + k];

    float acc = sb[c];
#pragma unroll
    for (int k = 0; k < IN_DIM; k++) acc += x[k] * sW[k * C + c];
    float res = lrelu(acc);
    float p = __shfl_xor(res, 1);
    if (!(c & 1)) hb[node * 32 + (c >> 1)] = pack_bf16(res, p);
}

// ---------------- CSR build (owner-partitioned: block b owns dst range (b&7)) ----------------
__global__ void hist_part(const int* __restrict__ dst, int* __restrict__ deg) {
    int owner = blockIdx.x & (NOWN - 1);
    int stripe = blockIdx.x >> 3;
    int lo = owner * OWN_RANGE, hi = lo + OWN_RANGE;
    int base = stripe * ESTRIPE;
    int end = base + ESTRIPE; if (end > NE) end = NE;
    for (int e = base + threadIdx.x; e < end; e += 256) {
        int d = dst[e];
        if (d >= lo && d < hi) atomicAdd(&deg[d], 1);
    }
}

__global__ void scan1_kernel(const int* __restrict__ deg,
                             int* __restrict__ excl,
                             int* __restrict__ bsum) {
    __shared__ int tmp[256];
    int tid = threadIdx.x;
    int i = blockIdx.x * 256 + tid;
    int v = (i < NN) ? deg[i] : 0;
    tmp[tid] = v;
    __syncthreads();
    for (int off = 1; off < 256; off <<= 1) {
        int t = (tid >= off) ? tmp[tid - off] : 0;
        __syncthreads();
        tmp[tid] += t;
        __syncthreads();
    }
    if (i < NN) excl[i] = tmp[tid] - v;
    if (tid == 255) bsum[blockIdx.x] = tmp[255];
}

__global__ void scan23_kernel(const int* __restrict__ excl,
                              const int* __restrict__ bsum,
                              int* __restrict__ row_start,
                              int* __restrict__ cursor) {
    __shared__ int s_off;
    int tid = threadIdx.x;
    if (tid < 64) {
        int p = 0;
        for (int i = tid; i < blockIdx.x; i += 64) p += bsum[i];
#pragma unroll
        for (int off = 32; off; off >>= 1) p += __shfl_xor(p, off);
        if (tid == 0) s_off = p;
    }
    __syncthreads();
    int i = blockIdx.x * 256 + tid;
    if (i < NN) {
        int v = excl[i] + s_off;
        row_start[i] = v;
        cursor[i] = v;
    }
}

// owner-partitioned fill: csr_src (4B) + csr-ordered bf16 edge_attr (32B) per edge
__global__ void fill_part(const int* __restrict__ src,
                          const int* __restrict__ dst,
                          const float* __restrict__ edge_attr,
                          int* __restrict__ cursor,
                          int* __restrict__ csr_src,
                          uint4v* __restrict__ csr_ea) {   // 2 × uint4 per slot
    int owner = blockIdx.x & (NOWN - 1);
    int stripe = blockIdx.x >> 3;
    int lo = owner * OWN_RANGE, hi = lo + OWN_RANGE;
    int base = stripe * ESTRIPE;
    int end = base + ESTRIPE; if (end > NE) end = NE;
    for (int e = base + threadIdx.x; e < end; e += 256) {
        int d = dst[e];
        if (d >= lo && d < hi) {
            int slot = atomicAdd(&cursor[d], 1);
            csr_src[slot] = src[e];
            const float4* ea = reinterpret_cast<const float4*>(edge_attr + e * IN_DIM);
            float4 f0 = ea[0], f1 = ea[1], f2 = ea[2];
            uint4v w0, w1;
            w0[0] = pack_bf16(f0.x, f0.y); w0[1] = pack_bf16(f0.z, f0.w);
            w0[2] = pack_bf16(f1.x, f1.y); w0[3] = pack_bf16(f1.z, f1.w);
            w1[0] = pack_bf16(f2.x, f2.y); w1[1] = pack_bf16(f2.z, f2.w);
            w1[2] = 0u; w1[3] = 0u;
            csr_ea[slot * 2] = w0;
            csr_ea[slot * 2 + 1] = w1;
        }
    }
}

// ---------------- weight prep: WT[l][col][k] bf16, K = [W_self; W_nbr; W_edge; 0] ----------------
__global__ void wprep_kernel(const float* __restrict__ W_self,
                             const float* __restrict__ W_nbr,
                             const float* __restrict__ W_edge,
                             unsigned short* __restrict__ WT) {
    int idx = blockIdx.x * 256 + threadIdx.x;   // 2*64*160 = 20480
    if (idx >= 2 * C * KTOT) return;
    int l = idx / (C * KTOT);
    int rem = idx % (C * KTOT);
    int col = rem / KTOT;
    int k = rem % KTOT;
    float v = 0.f;
    if (k < C)                    v = W_self[l * C * C + k * C + col];
    else if (k < 2 * C)           v = W_nbr[l * C * C + (k - C) * C + col];
    else if (k < 2 * C + IN_DIM)  v = W_edge[l * IN_DIM * C + (k - 2 * C) * C + col];
    WT[idx] = bf16r(v);
}

// ---------------- agg_e: coalesced sum of csr-ordered bf16 edge rows ----------------
__global__ void agg_e_kernel(const uint32_t* __restrict__ csr_ea,   // [NE][8] u32
                             const int* __restrict__ row_start,
                             const int* __restrict__ deg,
                             uint32_t* __restrict__ aggeb) {        // [NN][8] u32
    int tid = threadIdx.x;
    int node = blockIdx.x * (blockDim.x >> 6) + (tid >> 6);
    int lane = tid & 63;
    if (node >= NN) return;
    int start = row_start[node], cnt = deg[node];
    int eg = lane >> 3;        // 8 edge groups
    int comp = lane & 7;       // u32 component within a 32B edge row
    float s0 = 0.f, s1 = 0.f;
    for (int j = eg; j < cnt; j += 8) {
        uint32_t v = csr_ea[(size_t)(start + j) * 8 + comp];   // coalesced
        s0 += bflo(v); s1 += bfhi(v);
    }
    s0 += __shfl_xor(s0, 8);  s1 += __shfl_xor(s1, 8);
    s0 += __shfl_xor(s0, 16); s1 += __shfl_xor(s1, 16);
    s0 += __shfl_xor(s0, 32); s1 += __shfl_xor(s1, 32);
    if (lane < 8) aggeb[node * 8 + comp] = pack_bf16(s0, s1);
}

// ---------------- neighbor gather: aggb[n] = sum_{e in} hb[src] (bf16 rows) ----------------
__global__ void gather_kernel(const uint32_t* __restrict__ hb_in,
                              const int* __restrict__ row_start,
                              const int* __restrict__ deg,
                              const int* __restrict__ csr_src,
                              uint32_t* __restrict__ aggb) {
    int tid = threadIdx.x;
    int node = blockIdx.x * (blockDim.x >> 6) + (tid >> 6);
    int lane = tid & 63;
    if (node >= NN) return;

    int start = row_start[node], cnt = deg[node];
    int half = lane >> 5;
    int q = lane & 31;

    int myidx = (lane < cnt) ? csr_src[start + lane] : 0;
    int nb = cnt < 64 ? cnt : 64;

    float a0 = 0.f, a1 = 0.f, b0v = 0.f, b1v = 0.f;
    float c0 = 0.f, c1 = 0.f, d0 = 0.f, d1 = 0.f;
    int j = 0;
    for (; j + 16 <= nb; j += 16) {     // 8 independent loads in flight per half
        int p = j + 4 * half;
        int s0 = __shfl(myidx, p);
        int s1 = __shfl(myidx, p + 1);
        int s2 = __shfl(myidx, p + 2);
        int s3 = __shfl(myidx, p + 3);
        int s4 = __shfl(myidx, p + 8);
        int s5 = __shfl(myidx, p + 9);
        int s6 = __shfl(myidx, p + 10);
        int s7 = __shfl(myidx, p + 11);
        uint32_t v0 = hb_in[s0 * 32 + q];
        uint32_t v1 = hb_in[s1 * 32 + q];
        uint32_t v2 = hb_in[s2 * 32 + q];
        uint32_t v3 = hb_in[s3 * 32 + q];
        uint32_t v4 = hb_in[s4 * 32 + q];
        uint32_t v5 = hb_in[s5 * 32 + q];
        uint32_t v6 = hb_in[s6 * 32 + q];
        uint32_t v7 = hb_in[s7 * 32 + q];
        a0  += bflo(v0); a1  += bfhi(v0);
        b0v += bflo(v1); b1v += bfhi(v1);
        c0  += bflo(v2); c1  += bfhi(v2);
        d0  += bflo(v3); d1  += bfhi(v3);
        a0  += bflo(v4); a1  += bfhi(v4);
        b0v += bflo(v5); b1v += bfhi(v5);
        c0  += bflo(v6); c1  += bfhi(v6);
        d0  += bflo(v7); d1  += bfhi(v7);
    }
    for (; j + 8 <= nb; j += 8) {
        int p = j + 4 * half;
        int s0 = __shfl(myidx, p);
        int s1 = __shfl(myidx, p + 1);
        int s2 = __shfl(myidx, p + 2);
        int s3 = __shfl(myidx, p + 3);
        uint32_t v0 = hb_in[s0 * 32 + q];
        uint32_t v1 = hb_in[s1 * 32 + q];
        uint32_t v2 = hb_in[s2 * 32 + q];
        uint32_t v3 = hb_in[s3 * 32 + q];
        a0  += bflo(v0); a1  += bfhi(v0);
        b0v += bflo(v1); b1v += bfhi(v1);
        c0  += bflo(v2); c1  += bfhi(v2);
        d0  += bflo(v3); d1  += bfhi(v3);
    }
    for (; j + 2 <= nb; j += 2) {
        int s = __shfl(myidx, j + half);
        uint32_t v = hb_in[s * 32 + q];
        a0 += bflo(v); a1 += bfhi(v);
    }
    {
        int s = __shfl(myidx, (j < 64) ? j : 0);
        if (j < nb && half == 0) {
            uint32_t v = hb_in[s * 32 + q];
            a0 += bflo(v); a1 += bfhi(v);
        }
    }
    for (int i2 = 64 + half; i2 < cnt; i2 += 2) {
        int s = csr_src[start + i2];
        uint32_t v = hb_in[s * 32 + q];
        a0 += bflo(v); a1 += bfhi(v);
    }
    a0 += b0v + c0 + d0;
    a1 += b1v + c1 + d1;
    a0 += __shfl_xor(a0, 32);
    a1 += __shfl_xor(a1, 32);
    if (lane < 32) aggb[node * 32 + q] = pack_bf16(a0, a1);
}

// ---------------- MFMA node update: hb_out = lrelu([hbA|aggb|aggeb] @ Wcat + b) ----------------
// 16x16x32 bf16, K=160 (5 MFMA). Block = 512 thr = 8 waves = 2 M-tiles x 4 N-tiles.
__global__ __launch_bounds__(512) void gemm_kernel(
        const uint32_t* __restrict__ hbA,      // [NN][32] bf16 pairs (K 0..63)
        const uint32_t* __restrict__ aggb,     // [NN][32] bf16 pairs (K 64..127)
        const uint32_t* __restrict__ aggeb,    // [NN][8]  bf16 pairs (K 128..143, 12 live)
        const unsigned short* __restrict__ WT, // [64][160] bf16 (layer slice)
        const float* __restrict__ bias,        // b_conv layer slice [64]
        unsigned short* __restrict__ hb_out) { // [NN][64] bf16
    int tid = threadIdx.x;
    int w = tid >> 6;
    int l = tid & 63;
    int mt = blockIdx.x * 2 + (w >> 2);
    if (mt * 16 >= NN) return;
    int nt = w & 3;
    int node_base = mt * 16;

    int arow = l & 15;            // A row within tile / B col within tile
    int kg = l >> 4;              // k-group of 8
    int gcol = nt * 16 + arow;    // global output column for B/C

    const uint32_t* aptr = hbA + (node_base + arow) * 32 + kg * 4;
    const uint32_t* gptr = aggb + (node_base + arow) * 32 + kg * 4;
    short8 a0 = __builtin_bit_cast(short8, *reinterpret_cast<const uint4v*>(aptr));
    short8 a1 = __builtin_bit_cast(short8, *reinterpret_cast<const uint4v*>(aptr + 16));
    short8 a2 = __builtin_bit_cast(short8, *reinterpret_cast<const uint4v*>(gptr));
    short8 a3 = __builtin_bit_cast(short8, *reinterpret_cast<const uint4v*>(gptr + 16));
    short8 a4 = {0, 0, 0, 0, 0, 0, 0, 0};
    if (kg < 2)
        a4 = __builtin_bit_cast(short8, *reinterpret_cast<const uint4v*>(
                 aggeb + (node_base + arow) * 8 + kg * 4));

    const unsigned short* bbase = WT + gcol * KTOT + kg * 8;
    short8 b0 = __builtin_bit_cast(short8, *reinterpret_cast<const uint4v*>(bbase));
    short8 b1 = __builtin_bit_cast(short8, *reinterpret_cast<const uint4v*>(bbase + 32));
    short8 b2 = __builtin_bit_cast(short8, *reinterpret_cast<const uint4v*>(bbase + 64));
    short8 b3 = __builtin_bit_cast(short8, *reinterpret_cast<const uint4v*>(bbase + 96));
    short8 b4 = __builtin_bit_cast(short8, *reinterpret_cast<const uint4v*>(bbase + 128));

    float bv = bias[gcol];
    f32x4 acc = {bv, bv, bv, bv};

    acc = __builtin_amdgcn_mfma_f32_16x16x32_bf16(a0, b0, acc, 0, 0, 0);
    acc = __builtin_amdgcn_mfma_f32_16x16x32_bf16(a1, b1, acc, 0, 0, 0);
    acc = __builtin_amdgcn_mfma_f32_16x16x32_bf16(a2, b2, acc, 0, 0, 0);
    acc = __builtin_amdgcn_mfma_f32_16x16x32_bf16(a3, b3, acc, 0, 0, 0);
    acc = __builtin_amdgcn_mfma_f32_16x16x32_bf16(a4, b4, acc, 0, 0, 0);

#pragma unroll
    for (int r = 0; r < 4; r++) {
        float res = lrelu(acc[r]);
        hb_out[(node_base + kg * 4 + r) * C + gcol] = bf16r(res);
    }
}

// ---------------- read-out (bf16 h) ----------------
__global__ void readout_fused(const unsigned short* __restrict__ hb,
                              const float* __restrict__ W_out,
                              const float* __restrict__ b_out,
                              const int* __restrict__ batch,
                              float* __restrict__ sums,
                              float* __restrict__ counts) {
    __shared__ float s_sum[NG];
    __shared__ float s_cnt[NG];
    int tid = threadIdx.x;
    if (tid < NG) { s_sum[tid] = 0.f; s_cnt[tid] = 0.f; }
    __syncthreads();

    int lane = tid & 63;
    int wave = tid >> 6;
    int base = blockIdx.x * 256 + wave * 64;
    float w = W_out[lane];
    float b0 = b_out[0];

    if (base < NN) {
        int last = base + 63;
        bool full = (last < NN);
        int gf = batch[base];
        int gl = batch[full ? last : (NN - 1)];
        if (full && gf == gl) {
            float p = 0.f;
            for (int i = 0; i < 64; i++)
                p += __uint_as_float((uint32_t)hb[(base + i) * C + lane] << 16);
            p *= w;
#pragma unroll
            for (int off = 32; off; off >>= 1) p += __shfl_xor(p, off);
            if (lane == 0) {
                atomicAdd(&s_sum[gf], p + 64.f * b0);
                atomicAdd(&s_cnt[gf], 64.f);
            }
        } else {
            float y_local = 0.f;
            for (int i = 0; i < 64; i++) {
                int nd = base + i;
                float v = 0.f;
                if (nd < NN) v = __uint_as_float((uint32_t)hb[nd * C + lane] << 16) * w;
#pragma unroll
                for (int off = 32; off; off >>= 1) v += __shfl_xor(v, off);
                if (lane == i) y_local = v + b0;
            }
            int nd = base + lane;
            if (nd < NN) {
                int g = batch[nd];
                atomicAdd(&s_sum[g], y_local);
                atomicAdd(&s_cnt[g], 1.0f);
            }
        }
    }
    __syncthreads();
    if (tid < NG && s_cnt[tid] != 0.f) {
        atomicAdd(&sums[tid], s_sum[tid]);
        atomicAdd(&counts[tid], s_cnt[tid]);
    }
}

__global__ void finalize_kernel(const float* __restrict__ sums,
                                const float* __restrict__ counts,
                                float* __restrict__ out) {
    int g = threadIdx.x;
    if (g < NG) out[g] = sums[g] / fmaxf(counts[g], 1.0f);
}

extern "C" void kernel_launch(void* const* d_in, const int* in_sizes, int n_in,
                              void* d_out, int out_size, void* d_ws, size_t ws_size,
                              hipStream_t stream) {
    const float* state     = (const float*)d_in[0];
    const float* action    = (const float*)d_in[1];
    const int*   edge_index= (const int*)d_in[2];
    const float* edge_attr = (const float*)d_in[3];
    const int*   batch     = (const int*)d_in[4];
    const float* W_in      = (const float*)d_in[5];
    const float* b_in      = (const float*)d_in[6];
    const float* W_self    = (const float*)d_in[7];
    const float* W_nbr     = (const float*)d_in[8];
    const float* W_edge    = (const float*)d_in[9];
    const float* b_conv    = (const float*)d_in[10];
    const float* W_out     = (const float*)d_in[11];
    const float* b_out     = (const float*)d_in[12];
    float* out = (float*)d_out;

    const int* src = edge_index;
    const int* dst = edge_index + NE;

    // workspace layout (4-byte units; all 16B-aligned by construction)
    float* ws      = (float*)d_ws;
    float* sums    = ws;                      // NG
    float* counts  = sums + NG;               // NG
    int*   deg     = (int*)(counts + NG);     // NN
    int*   excl    = deg + NN;                // NN
    int*   row_start = excl + NN;             // NN
    int*   cursor  = row_start + NN;          // NN
    int*   bsum    = cursor + NN;             // 256
    int*   csr_src = bsum + 256;              // NE
    uint32_t* csr_ea = (uint32_t*)(csr_src + NE);   // NE*8 u32 (32B/edge)
    uint32_t* hb_a = csr_ea + (size_t)NE * 8; // NN*32
    uint32_t* hb_b = hb_a + NN * 32;          // NN*32
    uint32_t* aggb = hb_b + NN * 32;          // NN*32
    uint32_t* aggeb = aggb + NN * 32;         // NN*8
    unsigned short* WT = (unsigned short*)(aggeb + NN * 8);  // 2*64*160 bf16

    hipMemsetAsync(deg, 0, NN * sizeof(int), stream);
    hipMemsetAsync(sums, 0, 2 * NG * sizeof(float), stream);

    const int THREADS = 256;
    int node_blocks = (NN + 3) / 4;
    int part_blocks = NSTRIPES * NOWN;   // owner-partitioned edge kernels

    readin_kernel<<<node_blocks, THREADS, 0, stream>>>(state, action, W_in, b_in, hb_a);

    hist_part<<<part_blocks, THREADS, 0, stream>>>(dst, deg);
    scan1_kernel<<<SCAN_BLOCKS, 256, 0, stream>>>(deg, excl, bsum);
    scan23_kernel<<<SCAN_BLOCKS, 256, 0, stream>>>(excl, bsum, row_start, cursor);
    fill_part<<<part_blocks, THREADS, 0, stream>>>(src, dst, edge_attr, cursor,
                                                   csr_src, (uint4v*)csr_ea);

    wprep_kernel<<<80, 256, 0, stream>>>(W_self, W_nbr, W_edge, WT);

    agg_e_kernel<<<node_blocks, THREADS, 0, stream>>>(csr_ea, row_start, deg, aggeb);

    int gemm_blocks = (3125 + 1) / 2;   // 3125 M-tiles of 16 nodes, 2 per block

    // layer 0: hb_a -> hb_b
    gather_kernel<<<node_blocks, THREADS, 0, stream>>>(hb_a, row_start, deg, csr_src, aggb);
    gemm_kernel<<<gemm_blocks, 512, 0, stream>>>(
        hb_a, aggb, aggeb, WT, b_conv, (unsigned short*)hb_b);

    // layer 1: hb_b -> hb_a
    gather_kernel<<<node_blocks, THREADS, 0, stream>>>(hb_b, row_start, deg, csr_src, aggb);
    gemm_kernel<<<gemm_blocks, 512, 0, stream>>>(
        hb_b, aggb, aggeb, WT + C * KTOT, b_conv + C, (unsigned short*)hb_a);

    int ro_blocks = (NN + 255) / 256;
    readout_fused<<<ro_blocks, THREADS, 0, stream>>>(
        (const unsigned short*)hb_a, W_out, b_out, batch, sums, counts);
    finalize_kernel<<<1, 128, 0, stream>>>(sums, counts, out);
}

// Round 12
// 327.310 us; speedup vs baseline: 3.4264x; 1.0254x over previous
//
#include <hip/hip_runtime.h>

#define NN 50000
#define NE 800000
#define NG 128
#define IN_DIM 12
#define C 64
#define KTOT 160          // [h(64) | agg_h(64) | agg_e(12) + pad(20)]
#define NEG_SLOPE 0.01f
#define SCAN_BLOCKS 196   // ceil(NN/256)
#define NOWN 8            // XCD count: owner-partitioned scatter
#define OWN_RANGE 6250    // NN / NOWN (exact)
#define ESTRIPE 2048
#define NSTRIPES ((NE + ESTRIPE - 1) / ESTRIPE)   // 391

typedef short short8 __attribute__((ext_vector_type(8)));
typedef float f32x4 __attribute__((ext_vector_type(4)));
typedef unsigned int uint4v __attribute__((ext_vector_type(4)));

__device__ __forceinline__ float lrelu(float v) {
    return v > 0.f ? v : NEG_SLOPE * v;
}
__device__ __forceinline__ float bflo(uint32_t v) { return __uint_as_float(v << 16); }
__device__ __forceinline__ float bfhi(uint32_t v) { return __uint_as_float(v & 0xffff0000u); }
__device__ __forceinline__ unsigned short bf16r(float x) {   // RNE f32->bf16
    uint32_t u = __float_as_uint(x);
    u += 0x7fffu + ((u >> 16) & 1u);
    return (unsigned short)(u >> 16);
}
__device__ __forceinline__ uint32_t pack_bf16(float lo, float hi) {
    return (uint32_t)bf16r(lo) | ((uint32_t)bf16r(hi) << 16);
}

// ---------------- read-in: h (bf16 rows only) ----------------
__global__ void readin_kernel(const float* __restrict__ state,
                              const float* __restrict__ action,
                              const float* __restrict__ W_in,
                              const float* __restrict__ b_in,
                              uint32_t* __restrict__ hb) {
    __shared__ float sW[IN_DIM * C];
    __shared__ float sb[C];
    int tid = threadIdx.x;
    for (int i = tid; i < IN_DIM * C; i += blockDim.x) sW[i] = W_in[i];
    if (tid < C) sb[tid] = b_in[tid];
    __syncthreads();

    int node = blockIdx.x * (blockDim.x >> 6) + (tid >> 6);
    int c = tid & 63;
    if (node >= NN) return;

    float x[IN_DIM];
#pragma unroll
    for (int k = 0; k < 8; k++) x[k] = state[node * 8 + k];
#pragma unroll
    for (int k = 0; k < 4; k++) x[8 + k] = action[node * 4 + k];

    float acc = sb[c];
#pragma unroll
    for (int k = 0; k < IN_DIM; k++) acc += x[k] * sW[k * C + c];
    float res = lrelu(acc);
    float p = __shfl_xor(res, 1);
    if (!(c & 1)) hb[node * 32 + (c >> 1)] = pack_bf16(res, p);
}

// ---------------- sequential bf16 pack of edge_attr: ea6[NE][6] u32 ----------------
__global__ void pack_kernel(const float* __restrict__ edge_attr,
                            uint32_t* __restrict__ ea6) {
    int e = blockIdx.x * 256 + threadIdx.x;
    if (e >= NE) return;
    const float4* ea = reinterpret_cast<const float4*>(edge_attr + (size_t)e * IN_DIM);
    float4 f0 = ea[0], f1 = ea[1], f2 = ea[2];
    uint2* o = reinterpret_cast<uint2*>(ea6 + (size_t)e * 6);
    uint2 t;
    t.x = pack_bf16(f0.x, f0.y); t.y = pack_bf16(f0.z, f0.w); o[0] = t;
    t.x = pack_bf16(f1.x, f1.y); t.y = pack_bf16(f1.z, f1.w); o[1] = t;
    t.x = pack_bf16(f2.x, f2.y); t.y = pack_bf16(f2.z, f2.w); o[2] = t;
}

// ---------------- CSR build (owner-partitioned) ----------------
__global__ void hist_part(const int* __restrict__ dst, int* __restrict__ deg) {
    int owner = blockIdx.x & (NOWN - 1);
    int stripe = blockIdx.x >> 3;
    int lo = owner * OWN_RANGE, hi = lo + OWN_RANGE;
    int base = stripe * ESTRIPE;
    int end = base + ESTRIPE; if (end > NE) end = NE;
    for (int e = base + threadIdx.x; e < end; e += 256) {
        int d = dst[e];
        if (d >= lo && d < hi) atomicAdd(&deg[d], 1);
    }
}

__global__ void scan1_kernel(const int* __restrict__ deg,
                             int* __restrict__ excl,
                             int* __restrict__ bsum) {
    __shared__ int tmp[256];
    int tid = threadIdx.x;
    int i = blockIdx.x * 256 + tid;
    int v = (i < NN) ? deg[i] : 0;
    tmp[tid] = v;
    __syncthreads();
    for (int off = 1; off < 256; off <<= 1) {
        int t = (tid >= off) ? tmp[tid - off] : 0;
        __syncthreads();
        tmp[tid] += t;
        __syncthreads();
    }
    if (i < NN) excl[i] = tmp[tid] - v;
    if (tid == 255) bsum[blockIdx.x] = tmp[255];
}

__global__ void scan23_kernel(const int* __restrict__ excl,
                              const int* __restrict__ bsum,
                              int* __restrict__ row_start,
                              int* __restrict__ cursor) {
    __shared__ int s_off;
    int tid = threadIdx.x;
    if (tid < 64) {
        int p = 0;
        for (int i = tid; i < blockIdx.x; i += 64) p += bsum[i];
#pragma unroll
        for (int off = 32; off; off >>= 1) p += __shfl_xor(p, off);
        if (tid == 0) s_off = p;
    }
    __syncthreads();
    int i = blockIdx.x * 256 + tid;
    if (i < NN) {
        int v = excl[i] + s_off;
        row_start[i] = v;
        cursor[i] = v;
    }
}

// owner-partitioned fill: single 8B {src, eid} store per edge (XCD-local slots)
__global__ void fill_part(const int* __restrict__ src,
                          const int* __restrict__ dst,
                          int* __restrict__ cursor,
                          int2* __restrict__ csr2) {
    int owner = blockIdx.x & (NOWN - 1);
    int stripe = blockIdx.x >> 3;
    int lo = owner * OWN_RANGE, hi = lo + OWN_RANGE;
    int base = stripe * ESTRIPE;
    int end = base + ESTRIPE; if (end > NE) end = NE;
    for (int e = base + threadIdx.x; e < end; e += 256) {
        int d = dst[e];
        if (d >= lo && d < hi) {
            int slot = atomicAdd(&cursor[d], 1);
            csr2[slot] = make_int2(src[e], e);
        }
    }
}

// ---------------- weight prep: WT[l][col][k] bf16, K = [W_self; W_nbr; W_edge; 0] ----------------
__global__ void wprep_kernel(const float* __restrict__ W_self,
                             const float* __restrict__ W_nbr,
                             const float* __restrict__ W_edge,
                             unsigned short* __restrict__ WT) {
    int idx = blockIdx.x * 256 + threadIdx.x;   // 2*64*160 = 20480
    if (idx >= 2 * C * KTOT) return;
    int l = idx / (C * KTOT);
    int rem = idx % (C * KTOT);
    int col = rem / KTOT;
    int k = rem % KTOT;
    float v = 0.f;
    if (k < C)                    v = W_self[l * C * C + k * C + col];
    else if (k < 2 * C)           v = W_nbr[l * C * C + (k - C) * C + col];
    else if (k < 2 * C + IN_DIM)  v = W_edge[l * IN_DIM * C + (k - 2 * C) * C + col];
    WT[idx] = bf16r(v);
}

// ---------------- neighbor gather (+ fused agg_e on layer 0) ----------------
// aggb[n] = sum_in hb[src]; if doea: aggeb[n] = sum_in ea6[eid] (direct csr2.y loads)
__global__ void gather_kernel(const uint32_t* __restrict__ hb_in,
                              const int* __restrict__ row_start,
                              const int* __restrict__ deg,
                              const int2* __restrict__ csr2,
                              const uint32_t* __restrict__ ea6,
                              uint32_t* __restrict__ aggb,
                              uint32_t* __restrict__ aggeb,
                              int doea) {
    int tid = threadIdx.x;
    int node = blockIdx.x * (blockDim.x >> 6) + (tid >> 6);
    int lane = tid & 63;
    if (node >= NN) return;

    int start = row_start[node], cnt = deg[node];
    int half = lane >> 5;
    int q = lane & 31;

    int myidx = (lane < cnt) ? csr2[start + lane].x : 0;
    int nb = cnt < 64 ? cnt : 64;

    float a0 = 0.f, a1 = 0.f, b0v = 0.f, b1v = 0.f;
    float c0 = 0.f, c1 = 0.f, d0 = 0.f, d1 = 0.f;
    int j = 0;
    for (; j + 16 <= nb; j += 16) {     // 8 independent loads in flight per half
        int p = j + 4 * half;
        int s0 = __shfl(myidx, p);
        int s1 = __shfl(myidx, p + 1);
        int s2 = __shfl(myidx, p + 2);
        int s3 = __shfl(myidx, p + 3);
        int s4 = __shfl(myidx, p + 8);
        int s5 = __shfl(myidx, p + 9);
        int s6 = __shfl(myidx, p + 10);
        int s7 = __shfl(myidx, p + 11);
        uint32_t v0 = hb_in[s0 * 32 + q];
        uint32_t v1 = hb_in[s1 * 32 + q];
        uint32_t v2 = hb_in[s2 * 32 + q];
        uint32_t v3 = hb_in[s3 * 32 + q];
        uint32_t v4 = hb_in[s4 * 32 + q];
        uint32_t v5 = hb_in[s5 * 32 + q];
        uint32_t v6 = hb_in[s6 * 32 + q];
        uint32_t v7 = hb_in[s7 * 32 + q];
        a0  += bflo(v0); a1  += bfhi(v0);
        b0v += bflo(v1); b1v += bfhi(v1);
        c0  += bflo(v2); c1  += bfhi(v2);
        d0  += bflo(v3); d1  += bfhi(v3);
        a0  += bflo(v4); a1  += bfhi(v4);
        b0v += bflo(v5); b1v += bfhi(v5);
        c0  += bflo(v6); c1  += bfhi(v6);
        d0  += bflo(v7); d1  += bfhi(v7);
    }
    for (; j + 8 <= nb; j += 8) {
        int p = j + 4 * half;
        int s0 = __shfl(myidx, p);
        int s1 = __shfl(myidx, p + 1);
        int s2 = __shfl(myidx, p + 2);
        int s3 = __shfl(myidx, p + 3);
        uint32_t v0 = hb_in[s0 * 32 + q];
        uint32_t v1 = hb_in[s1 * 32 + q];
        uint32_t v2 = hb_in[s2 * 32 + q];
        uint32_t v3 = hb_in[s3 * 32 + q];
        a0  += bflo(v0); a1  += bfhi(v0);
        b0v += bflo(v1); b1v += bfhi(v1);
        c0  += bflo(v2); c1  += bfhi(v2);
        d0  += bflo(v3); d1  += bfhi(v3);
    }
    for (; j + 2 <= nb; j += 2) {
        int s = __shfl(myidx, j + half);
        uint32_t v = hb_in[s * 32 + q];
        a0 += bflo(v); a1 += bfhi(v);
    }
    {
        int s = __shfl(myidx, (j < 64) ? j : 0);
        if (j < nb && half == 0) {
            uint32_t v = hb_in[s * 32 + q];
            a0 += bflo(v); a1 += bfhi(v);
        }
    }
    for (int i2 = 64 + half; i2 < cnt; i2 += 2) {
        int s = csr2[start + i2].x;
        uint32_t v = hb_in[s * 32 + q];
        a0 += bflo(v); a1 += bfhi(v);
    }

    if (doea) {
        // fused agg_e: 8 groups of 8 lanes; comp = u32 component of 24B ea row.
        // Direct csr2.y loads (L2-hot; broadcast within comp-group).
        int g = lane >> 3;
        int comp = lane & 7;
        float e0 = 0.f, e1 = 0.f;
        for (int j2 = g; j2 < cnt; j2 += 8) {
            int eid = csr2[start + j2].y;
            if (comp < 6) {
                uint32_t v = ea6[(size_t)eid * 6 + comp];
                e0 += bflo(v); e1 += bfhi(v);
            }
        }
        e0 += __shfl_xor(e0, 8);  e1 += __shfl_xor(e1, 8);
        e0 += __shfl_xor(e0, 16); e1 += __shfl_xor(e1, 16);
        e0 += __shfl_xor(e0, 32); e1 += __shfl_xor(e1, 32);
        if (lane < 8) aggeb[node * 8 + lane] = (lane < 6) ? pack_bf16(e0, e1) : 0u;
    }

    a0 += b0v + c0 + d0;
    a1 += b1v + c1 + d1;
    a0 += __shfl_xor(a0, 32);
    a1 += __shfl_xor(a1, 32);
    if (lane < 32) aggb[node * 32 + q] = pack_bf16(a0, a1);
}

// ---------------- MFMA node update: hb_out = lrelu([hbA|aggb|aggeb] @ Wcat + b) ----------------
__global__ __launch_bounds__(512) void gemm_kernel(
        const uint32_t* __restrict__ hbA,      // [NN][32] bf16 pairs (K 0..63)
        const uint32_t* __restrict__ aggb,     // [NN][32] bf16 pairs (K 64..127)
        const uint32_t* __restrict__ aggeb,    // [NN][8]  bf16 pairs (K 128..143, 12 live)
        const unsigned short* __restrict__ WT, // [64][160] bf16 (layer slice)
        const float* __restrict__ bias,        // b_conv layer slice [64]
        unsigned short* __restrict__ hb_out) { // [NN][64] bf16
    int tid = threadIdx.x;
    int w = tid >> 6;
    int l = tid & 63;
    int mt = blockIdx.x * 2 + (w >> 2);
    if (mt * 16 >= NN) return;
    int nt = w & 3;
    int node_base = mt * 16;

    int arow = l & 15;
    int kg = l >> 4;
    int gcol = nt * 16 + arow;

    const uint32_t* aptr = hbA + (node_base + arow) * 32 + kg * 4;
    const uint32_t* gptr = aggb + (node_base + arow) * 32 + kg * 4;
    short8 a0 = __builtin_bit_cast(short8, *reinterpret_cast<const uint4v*>(aptr));
    short8 a1 = __builtin_bit_cast(short8, *reinterpret_cast<const uint4v*>(aptr + 16));
    short8 a2 = __builtin_bit_cast(short8, *reinterpret_cast<const uint4v*>(gptr));
    short8 a3 = __builtin_bit_cast(short8, *reinterpret_cast<const uint4v*>(gptr + 16));
    short8 a4 = {0, 0, 0, 0, 0, 0, 0, 0};
    if (kg < 2)
        a4 = __builtin_bit_cast(short8, *reinterpret_cast<const uint4v*>(
                 aggeb + (node_base + arow) * 8 + kg * 4));

    const unsigned short* bbase = WT + gcol * KTOT + kg * 8;
    short8 b0 = __builtin_bit_cast(short8, *reinterpret_cast<const uint4v*>(bbase));
    short8 b1 = __builtin_bit_cast(short8, *reinterpret_cast<const uint4v*>(bbase + 32));
    short8 b2 = __builtin_bit_cast(short8, *reinterpret_cast<const uint4v*>(bbase + 64));
    short8 b3 = __builtin_bit_cast(short8, *reinterpret_cast<const uint4v*>(bbase + 96));
    short8 b4 = __builtin_bit_cast(short8, *reinterpret_cast<const uint4v*>(bbase + 128));

    float bv = bias[gcol];
    f32x4 acc = {bv, bv, bv, bv};

    acc = __builtin_amdgcn_mfma_f32_16x16x32_bf16(a0, b0, acc, 0, 0, 0);
    acc = __builtin_amdgcn_mfma_f32_16x16x32_bf16(a1, b1, acc, 0, 0, 0);
    acc = __builtin_amdgcn_mfma_f32_16x16x32_bf16(a2, b2, acc, 0, 0, 0);
    acc = __builtin_amdgcn_mfma_f32_16x16x32_bf16(a3, b3, acc, 0, 0, 0);
    acc = __builtin_amdgcn_mfma_f32_16x16x32_bf16(a4, b4, acc, 0, 0, 0);

#pragma unroll
    for (int r = 0; r < 4; r++) {
        float res = lrelu(acc[r]);
        hb_out[(node_base + kg * 4 + r) * C + gcol] = bf16r(res);
    }
}

// ---------------- read-out (bf16 h) ----------------
__global__ void readout_fused(const unsigned short* __restrict__ hb,
                              const float* __restrict__ W_out,
                              const float* __restrict__ b_out,
                              const int* __restrict__ batch,
                              float* __restrict__ sums,
                              float* __restrict__ counts) {
    __shared__ float s_sum[NG];
    __shared__ float s_cnt[NG];
    int tid = threadIdx.x;
    if (tid < NG) { s_sum[tid] = 0.f; s_cnt[tid] = 0.f; }
    __syncthreads();

    int lane = tid & 63;
    int wave = tid >> 6;
    int base = blockIdx.x * 256 + wave * 64;
    float w = W_out[lane];
    float b0 = b_out[0];

    if (base < NN) {
        int last = base + 63;
        bool full = (last < NN);
        int gf = batch[base];
        int gl = batch[full ? last : (NN - 1)];
        if (full && gf == gl) {
            float p = 0.f;
            for (int i = 0; i < 64; i++)
                p += __uint_as_float((uint32_t)hb[(base + i) * C + lane] << 16);
            p *= w;
#pragma unroll
            for (int off = 32; off; off >>= 1) p += __shfl_xor(p, off);
            if (lane == 0) {
                atomicAdd(&s_sum[gf], p + 64.f * b0);
                atomicAdd(&s_cnt[gf], 64.f);
            }
        } else {
            float y_local = 0.f;
            for (int i = 0; i < 64; i++) {
                int nd = base + i;
                float v = 0.f;
                if (nd < NN) v = __uint_as_float((uint32_t)hb[nd * C + lane] << 16) * w;
#pragma unroll
                for (int off = 32; off; off >>= 1) v += __shfl_xor(v, off);
                if (lane == i) y_local = v + b0;
            }
            int nd = base + lane;
            if (nd < NN) {
                int g = batch[nd];
                atomicAdd(&s_sum[g], y_local);
                atomicAdd(&s_cnt[g], 1.0f);
            }
        }
    }
    __syncthreads();
    if (tid < NG && s_cnt[tid] != 0.f) {
        atomicAdd(&sums[tid], s_sum[tid]);
        atomicAdd(&counts[tid], s_cnt[tid]);
    }
}

__global__ void finalize_kernel(const float* __restrict__ sums,
                                const float* __restrict__ counts,
                                float* __restrict__ out) {
    int g = threadIdx.x;
    if (g < NG) out[g] = sums[g] / fmaxf(counts[g], 1.0f);
}

extern "C" void kernel_launch(void* const* d_in, const int* in_sizes, int n_in,
                              void* d_out, int out_size, void* d_ws, size_t ws_size,
                              hipStream_t stream) {
    const float* state     = (const float*)d_in[0];
    const float* action    = (const float*)d_in[1];
    const int*   edge_index= (const int*)d_in[2];
    const float* edge_attr = (const float*)d_in[3];
    const int*   batch     = (const int*)d_in[4];
    const float* W_in      = (const float*)d_in[5];
    const float* b_in      = (const float*)d_in[6];
    const float* W_self    = (const float*)d_in[7];
    const float* W_nbr     = (const float*)d_in[8];
    const float* W_edge    = (const float*)d_in[9];
    const float* b_conv    = (const float*)d_in[10];
    const float* W_out     = (const float*)d_in[11];
    const float* b_out     = (const float*)d_in[12];
    float* out = (float*)d_out;

    const int* src = edge_index;
    const int* dst = edge_index + NE;

    // workspace layout (4-byte units; all sub-arrays 16B-aligned)
    float* ws      = (float*)d_ws;
    float* sums    = ws;                      // NG
    float* counts  = sums + NG;               // NG
    int*   deg     = (int*)(counts + NG);     // NN
    int*   excl    = deg + NN;                // NN
    int*   row_start = excl + NN;             // NN
    int*   cursor  = row_start + NN;          // NN
    int*   bsum    = cursor + NN;             // 256
    int2*  csr2    = (int2*)(bsum + 256);     // NE int2 (8B)
    uint32_t* ea6  = (uint32_t*)(csr2 + NE);  // NE*6 u32 (24B bf16 rows)
    uint32_t* hb_a = ea6 + (size_t)NE * 6;    // NN*32
    uint32_t* hb_b = hb_a + NN * 32;          // NN*32
    uint32_t* aggb = hb_b + NN * 32;          // NN*32
    uint32_t* aggeb = aggb + NN * 32;         // NN*8
    unsigned short* WT = (unsigned short*)(aggeb + NN * 8);  // 2*64*160 bf16

    hipMemsetAsync(deg, 0, NN * sizeof(int), stream);
    hipMemsetAsync(sums, 0, 2 * NG * sizeof(float), stream);

    const int THREADS = 256;
    int node_blocks = (NN + 3) / 4;
    int part_blocks = NSTRIPES * NOWN;
    int pack_blocks = (NE + THREADS - 1) / THREADS;

    readin_kernel<<<node_blocks, THREADS, 0, stream>>>(state, action, W_in, b_in, hb_a);
    pack_kernel<<<pack_blocks, THREADS, 0, stream>>>(edge_attr, ea6);

    hist_part<<<part_blocks, THREADS, 0, stream>>>(dst, deg);
    scan1_kernel<<<SCAN_BLOCKS, 256, 0, stream>>>(deg, excl, bsum);
    scan23_kernel<<<SCAN_BLOCKS, 256, 0, stream>>>(excl, bsum, row_start, cursor);
    fill_part<<<part_blocks, THREADS, 0, stream>>>(src, dst, cursor, csr2);

    wprep_kernel<<<80, 256, 0, stream>>>(W_self, W_nbr, W_edge, WT);

    int gemm_blocks = (3125 + 1) / 2;

    // layer 0: hb_a -> hb_b  (+ fused agg_e)
    gather_kernel<<<node_blocks, THREADS, 0, stream>>>(
        hb_a, row_start, deg, csr2, ea6, aggb, aggeb, 1);
    gemm_kernel<<<gemm_blocks, 512, 0, stream>>>(
        hb_a, aggb, aggeb, WT, b_conv, (unsigned short*)hb_b);

    // layer 1: hb_b -> hb_a
    gather_kernel<<<node_blocks, THREADS, 0, stream>>>(
        hb_b, row_start, deg, csr2, ea6, aggb, aggeb, 0);
    gemm_kernel<<<gemm_blocks, 512, 0, stream>>>(
        hb_b, aggb, aggeb, WT + C * KTOT, b_conv + C, (unsigned short*)hb_a);

    int ro_blocks = (NN + 255) / 256;
    readout_fused<<<ro_blocks, THREADS, 0, stream>>>(
        (const unsigned short*)hb_a, W_out, b_out, batch, sums, counts);
    finalize_kernel<<<1, 128, 0, stream>>>(sums, counts, out);
}